// Round 7
// baseline (659.980 us; speedup 1.0000x reference)
//
#include <hip/hip_runtime.h>
#include <hip/hip_bf16.h>
#include <math.h>

#define NEG_SLOPE 0.2f

typedef unsigned short ushortT;
typedef __attribute__((ext_vector_type(8))) short short8;   // 8 bf16 = 4 VGPRs (MFMA A/B frag)
typedef __attribute__((ext_vector_type(4))) float f32x4;    // MFMA C/D frag

static __device__ __forceinline__ float leaky(float x){ return x > 0.f ? x : NEG_SLOPE * x; }
static __device__ __forceinline__ float elu(float x){ return x > 0.f ? x : (__expf(x) - 1.f); }

// bf16 helpers: RNE pack, exact unpack
static __device__ __forceinline__ ushortT f2bf(float f){
  unsigned u = __float_as_uint(f);
  u += 0x7fff + ((u >> 16) & 1);
  return (ushortT)(u >> 16);
}
static __device__ __forceinline__ float bf2f(ushortT h){ return __uint_as_float((unsigned)h << 16); }
static __device__ __forceinline__ float bf_lo(unsigned u){ return __uint_as_float(u << 16); }
static __device__ __forceinline__ float bf_hi(unsigned u){ return __uint_as_float(u & 0xffff0000u); }

// ---------------- edge sort by dst (counting sort) ----------------
__global__ void hist_kernel(const int* __restrict__ dst, int E, int* __restrict__ counts){
  int i = blockIdx.x*blockDim.x + threadIdx.x;
  if(i < E) atomicAdd(&counts[dst[i]], 1);
}

__global__ void scan1_kernel(const int* __restrict__ counts, int N,
                             int* __restrict__ offsets, int* __restrict__ blocksums){
  __shared__ int sdata[1024];
  int i = blockIdx.x*1024 + threadIdx.x;
  int v = (i<N) ? counts[i] : 0;
  sdata[threadIdx.x] = v;
  __syncthreads();
  for(int off=1; off<1024; off<<=1){
    int t = (threadIdx.x >= off) ? sdata[threadIdx.x-off] : 0;
    __syncthreads();
    sdata[threadIdx.x] += t;
    __syncthreads();
  }
  if(i<N) offsets[i] = sdata[threadIdx.x] - v;
  if(threadIdx.x==1023) blocksums[blockIdx.x] = sdata[1023];
}

__global__ void scan2_kernel(int* __restrict__ blocksums, int nb){
  __shared__ int sdata[64];
  int v = ((int)threadIdx.x < nb) ? blocksums[threadIdx.x] : 0;
  sdata[threadIdx.x] = v;
  __syncthreads();
  for(int off=1; off<64; off<<=1){
    int t = (threadIdx.x >= off) ? sdata[threadIdx.x-off] : 0;
    __syncthreads();
    sdata[threadIdx.x] += t;
    __syncthreads();
  }
  if((int)threadIdx.x < nb) blocksums[threadIdx.x] = sdata[threadIdx.x] - v;
}

__global__ void scan3_kernel(int* __restrict__ offsets, const int* __restrict__ blocksums,
                             int N, int E, int* __restrict__ cursor){
  int i = blockIdx.x*1024 + threadIdx.x;
  if(i < N){
    int o = offsets[i] + blocksums[blockIdx.x];
    offsets[i] = o;
    cursor[i] = o;
  }
  if(i == 0) offsets[N] = E;
}

__global__ void scatter_kernel(const int* __restrict__ src, const int* __restrict__ dst, int E,
                               int* __restrict__ cursor, int* __restrict__ ssrc,
                               int* __restrict__ sdst){
  int i = blockIdx.x*blockDim.x + threadIdx.x;
  if(i < E){
    int d = dst[i];
    int p = atomicAdd(&cursor[d], 1);
    ssrc[p] = src[i];
    sdst[p] = d;
  }
}

// ---------------- W pre-transpose + bf16 hi/lo split: W[K,N] -> Wt[Npad][K] ----------------
__global__ __launch_bounds__(256) void wsplit_kernel(const float* __restrict__ W, int N,
                              ushortT* __restrict__ Wth, ushortT* __restrict__ Wtl){
  int idx = blockIdx.x*256 + threadIdx.x;   // over 256*256
  int n = idx >> 8, k = idx & 255;
  float v = (n < N) ? W[(size_t)k*N + n] : 0.f;
  ushortT h = f2bf(v);
  ushortT l = f2bf(v - bf2f(h));
  Wth[idx] = h; Wtl[idx] = l;
}

// ---------------- x split: fp32 [M][256] -> hi/lo bf16 planes ----------------
__global__ __launch_bounds__(256) void xsplit_kernel(const float4* __restrict__ x4,
                              ushortT* __restrict__ Xh, ushortT* __restrict__ Xl, int total4){
  int i = blockIdx.x*256 + threadIdx.x;
  if(i >= total4) return;
  float4 v = x4[i];
  ushortT h0=f2bf(v.x), h1=f2bf(v.y), h2=f2bf(v.z), h3=f2bf(v.w);
  ushort4 hv = make_ushort4(h0,h1,h2,h3);
  ushort4 lv = make_ushort4(f2bf(v.x-bf2f(h0)), f2bf(v.y-bf2f(h1)),
                            f2bf(v.z-bf2f(h2)), f2bf(v.w-bf2f(h3)));
  *(ushort4*)&Xh[(size_t)i*4] = hv;
  *(ushort4*)&Xl[(size_t)i*4] = lv;
}

// ---------------- bf16x3 MFMA GEMM, LDS-free: C[M,N] = A[M,256] @ B[256,N] ----------------
// A pre-split hi/lo bf16 [M][256] row-major; B pre-split [256 rows n][256 k] (n-major).
// Block = 4 waves stacked in M; wave tile 64(M) x 128(N); frags loaded DIRECT from
// global (L2/L3-resident) -> zero LDS, zero barriers. K fixed at 256.
__global__ __launch_bounds__(256, 2) void gemm_direct(const ushortT* __restrict__ Ah,
                       const ushortT* __restrict__ Al,
                       const ushortT* __restrict__ Bth, const ushortT* __restrict__ Btl,
                       ushortT* __restrict__ Cm, int M, int N){
  const int lane = threadIdx.x & 63;
  const int wv   = threadIdx.x >> 6;
  const int l15  = lane & 15, quad = lane >> 4;
  const int m0   = (blockIdx.y*4 + wv) * 64;
  const int n0   = blockIdx.x * 128;

  f32x4 acc[4][8];
  #pragma unroll
  for(int i=0;i<4;i++)
    #pragma unroll
    for(int j=0;j<8;j++){ acc[i][j][0]=0.f; acc[i][j][1]=0.f; acc[i][j][2]=0.f; acc[i][j][3]=0.f; }

  size_t arow[4];
  #pragma unroll
  for(int i=0;i<4;i++){
    int m = m0 + i*16 + l15;
    arow[i] = (size_t)(m < M ? m : M-1) * 256;
  }
  size_t brow[8];
  #pragma unroll
  for(int j=0;j<8;j++) brow[j] = (size_t)(n0 + j*16 + l15) * 256;

  #pragma unroll
  for(int t=0; t<8; t++){
    const int ko = t*32 + quad*8;
    short8 a_h[4], a_l[4];
    #pragma unroll
    for(int i=0;i<4;i++){
      a_h[i] = *(const short8*)&Ah[arow[i] + ko];
      a_l[i] = *(const short8*)&Al[arow[i] + ko];
    }
    #pragma unroll
    for(int j=0;j<8;j++){
      short8 b_h = *(const short8*)&Bth[brow[j] + ko];
      short8 b_l = *(const short8*)&Btl[brow[j] + ko];
      #pragma unroll
      for(int i=0;i<4;i++){
        acc[i][j] = __builtin_amdgcn_mfma_f32_16x16x32_bf16(a_h[i], b_h, acc[i][j], 0,0,0);
        acc[i][j] = __builtin_amdgcn_mfma_f32_16x16x32_bf16(a_h[i], b_l, acc[i][j], 0,0,0);
        acc[i][j] = __builtin_amdgcn_mfma_f32_16x16x32_bf16(a_l[i], b_h, acc[i][j], 0,0,0);
      }
    }
  }
  // C/D layout: col = lane&15, row = quad*4 + r
  #pragma unroll
  for(int i=0;i<4;i++){
    #pragma unroll
    for(int r=0;r<4;r++){
      int gm = m0 + i*16 + quad*4 + r;
      if(gm >= M) continue;
      #pragma unroll
      for(int j=0;j<8;j++){
        int gn = n0 + j*16 + l15;
        if(gn < N) Cm[(size_t)gm*N + gn] = f2bf(acc[i][j][r]);
      }
    }
  }
}

// ---------------- el/er projection from bf16 feat ----------------
__global__ void attn_proj_bf(const __hip_bfloat16* __restrict__ feat, const float* __restrict__ a_l,
                             const float* __restrict__ a_r, float* __restrict__ el,
                             float* __restrict__ er, int D){
  int n = blockIdx.x;
  int h = threadIdx.x >> 6;
  int lane = threadIdx.x & 63;
  float vl = 0.f, vr = 0.f;
  for(int d=lane; d<D; d+=64){
    float f = (float)feat[(size_t)n*4*D + h*D + d];
    vl = fmaf(f, a_l[h*D+d], vl);
    vr = fmaf(f, a_r[h*D+d], vr);
  }
  #pragma unroll
  for(int off=32; off; off>>=1){ vl += __shfl_down(vl,off); vr += __shfl_down(vr,off); }
  if(lane==0){ el[n*4+h] = vl; er[n*4+h] = vr; }
}

// ---------------- per-edge softmax numerators (all 4 heads) ----------------
__global__ __launch_bounds__(256) void edge_w_kernel(const int* __restrict__ ssrc,
                              const int* __restrict__ sdst, int E,
                              const float4* __restrict__ el4, const float4* __restrict__ er4,
                              float4* __restrict__ ew){
  int e = blockIdx.x*blockDim.x + threadIdx.x;
  if(e >= E) return;
  int s = ssrc[e], d = sdst[e];
  float4 l = el4[s], r = er4[d];
  float4 w;
  w.x = __expf(leaky(l.x + r.x));
  w.y = __expf(leaky(l.y + r.y));
  w.z = __expf(leaky(l.z + r.z));
  w.w = __expf(leaky(l.w + r.w));
  ew[e] = w;
}

// ---------------- softmax + aggregate, layers 0/1 (H*D=256 bf16), ELU ----------------
// one WAVE per dst node; writes next-layer A pre-split as hi/lo bf16 planes
__global__ __launch_bounds__(256) void agg_kernel(const uint2* __restrict__ feat2,
                           const float* __restrict__ ew,
                           const int* __restrict__ offsets, const int* __restrict__ ssrc,
                           const float* __restrict__ bias,
                           ushortT* __restrict__ Hh, ushortT* __restrict__ Hl, int N){
  int wv = threadIdx.x >> 6;
  int lane = threadIdx.x & 63;
  int n = blockIdx.x*4 + wv;
  if(n >= N) return;
  int h = lane >> 4;
  int e0 = offsets[n], e1 = offsets[n+1];
  float4 acc0 = make_float4(0.f,0.f,0.f,0.f), acc1 = acc0, acc2 = acc0, acc3 = acc0;
  float den0 = 0.f, den1 = 0.f, den2 = 0.f, den3 = 0.f;
  int e = e0;
  for(; e+3 < e1; e += 4){
    int s0 = ssrc[e], s1 = ssrc[e+1], s2 = ssrc[e+2], s3 = ssrc[e+3];
    float w0 = ew[(size_t)e*4 + h];
    float w1 = ew[(size_t)(e+1)*4 + h];
    float w2 = ew[(size_t)(e+2)*4 + h];
    float w3 = ew[(size_t)(e+3)*4 + h];
    uint2 q0 = feat2[(size_t)s0*64 + lane];
    uint2 q1 = feat2[(size_t)s1*64 + lane];
    uint2 q2 = feat2[(size_t)s2*64 + lane];
    uint2 q3 = feat2[(size_t)s3*64 + lane];
    acc0.x = fmaf(w0,bf_lo(q0.x),acc0.x); acc0.y = fmaf(w0,bf_hi(q0.x),acc0.y);
    acc0.z = fmaf(w0,bf_lo(q0.y),acc0.z); acc0.w = fmaf(w0,bf_hi(q0.y),acc0.w); den0 += w0;
    acc1.x = fmaf(w1,bf_lo(q1.x),acc1.x); acc1.y = fmaf(w1,bf_hi(q1.x),acc1.y);
    acc1.z = fmaf(w1,bf_lo(q1.y),acc1.z); acc1.w = fmaf(w1,bf_hi(q1.y),acc1.w); den1 += w1;
    acc2.x = fmaf(w2,bf_lo(q2.x),acc2.x); acc2.y = fmaf(w2,bf_hi(q2.x),acc2.y);
    acc2.z = fmaf(w2,bf_lo(q2.y),acc2.z); acc2.w = fmaf(w2,bf_hi(q2.y),acc2.w); den2 += w2;
    acc3.x = fmaf(w3,bf_lo(q3.x),acc3.x); acc3.y = fmaf(w3,bf_hi(q3.x),acc3.y);
    acc3.z = fmaf(w3,bf_lo(q3.y),acc3.z); acc3.w = fmaf(w3,bf_hi(q3.y),acc3.w); den3 += w3;
  }
  for(; e < e1; e++){
    int s = ssrc[e];
    float w = ew[(size_t)e*4 + h];
    uint2 q = feat2[(size_t)s*64 + lane];
    acc0.x = fmaf(w,bf_lo(q.x),acc0.x); acc0.y = fmaf(w,bf_hi(q.x),acc0.y);
    acc0.z = fmaf(w,bf_lo(q.y),acc0.z); acc0.w = fmaf(w,bf_hi(q.y),acc0.w); den0 += w;
  }
  float denom = (den0+den1) + (den2+den3);
  float4 acc;
  acc.x = (acc0.x+acc1.x) + (acc2.x+acc3.x);
  acc.y = (acc0.y+acc1.y) + (acc2.y+acc3.y);
  acc.z = (acc0.z+acc1.z) + (acc2.z+acc3.z);
  acc.w = (acc0.w+acc1.w) + (acc2.w+acc3.w);
  float inv = 1.f / fmaxf(denom, 1e-9f);
  float4 b4 = *(const float4*)&bias[lane*4];
  float o0 = elu(acc.x*inv + b4.x);
  float o1 = elu(acc.y*inv + b4.y);
  float o2 = elu(acc.z*inv + b4.z);
  float o3 = elu(acc.w*inv + b4.w);
  ushortT h0=f2bf(o0), h1=f2bf(o1), h2=f2bf(o2), h3=f2bf(o3);
  ushort4 hv = make_ushort4(h0,h1,h2,h3);
  ushort4 lv = make_ushort4(f2bf(o0-bf2f(h0)), f2bf(o1-bf2f(h1)),
                            f2bf(o2-bf2f(h2)), f2bf(o3-bf2f(h3)));
  *(ushort4*)&Hh[(size_t)n*256 + lane*4] = hv;
  *(ushort4*)&Hl[(size_t)n*256 + lane*4] = lv;
}

// ---------------- layer 2: aggregate (H*C=160 bf16) + head-mean logits ----------------
__global__ __launch_bounds__(256) void agg2_kernel(const uint2* __restrict__ feat2,
                            const float* __restrict__ ew,
                            const int* __restrict__ offsets, const int* __restrict__ ssrc,
                            const float* __restrict__ bias, float* __restrict__ logits, int N){
  __shared__ float s_out[4][160];
  int wv = threadIdx.x >> 6;
  int lane = threadIdx.x & 63;
  int n = blockIdx.x*4 + wv;
  bool valid = (n < N);
  if(valid && lane < 40){
    int h = lane / 10;
    int e0 = offsets[n], e1 = offsets[n+1];
    float4 acc0 = make_float4(0.f,0.f,0.f,0.f), acc1 = acc0, acc2 = acc0, acc3 = acc0;
    float den0 = 0.f, den1 = 0.f, den2 = 0.f, den3 = 0.f;
    int e = e0;
    for(; e+3 < e1; e += 4){
      int s0 = ssrc[e], s1 = ssrc[e+1], s2 = ssrc[e+2], s3 = ssrc[e+3];
      float w0 = ew[(size_t)e*4 + h];
      float w1 = ew[(size_t)(e+1)*4 + h];
      float w2 = ew[(size_t)(e+2)*4 + h];
      float w3 = ew[(size_t)(e+3)*4 + h];
      uint2 q0 = feat2[(size_t)s0*40 + lane];
      uint2 q1 = feat2[(size_t)s1*40 + lane];
      uint2 q2 = feat2[(size_t)s2*40 + lane];
      uint2 q3 = feat2[(size_t)s3*40 + lane];
      acc0.x = fmaf(w0,bf_lo(q0.x),acc0.x); acc0.y = fmaf(w0,bf_hi(q0.x),acc0.y);
      acc0.z = fmaf(w0,bf_lo(q0.y),acc0.z); acc0.w = fmaf(w0,bf_hi(q0.y),acc0.w); den0 += w0;
      acc1.x = fmaf(w1,bf_lo(q1.x),acc1.x); acc1.y = fmaf(w1,bf_hi(q1.x),acc1.y);
      acc1.z = fmaf(w1,bf_lo(q1.y),acc1.z); acc1.w = fmaf(w1,bf_hi(q1.y),acc1.w); den1 += w1;
      acc2.x = fmaf(w2,bf_lo(q2.x),acc2.x); acc2.y = fmaf(w2,bf_hi(q2.x),acc2.y);
      acc2.z = fmaf(w2,bf_lo(q2.y),acc2.z); acc2.w = fmaf(w2,bf_hi(q2.y),acc2.w); den2 += w2;
      acc3.x = fmaf(w3,bf_lo(q3.x),acc3.x); acc3.y = fmaf(w3,bf_hi(q3.x),acc3.y);
      acc3.z = fmaf(w3,bf_lo(q3.y),acc3.z); acc3.w = fmaf(w3,bf_hi(q3.y),acc3.w); den3 += w3;
    }
    for(; e < e1; e++){
      int s = ssrc[e];
      float w = ew[(size_t)e*4 + h];
      uint2 q = feat2[(size_t)s*40 + lane];
      acc0.x = fmaf(w,bf_lo(q.x),acc0.x); acc0.y = fmaf(w,bf_hi(q.x),acc0.y);
      acc0.z = fmaf(w,bf_lo(q.y),acc0.z); acc0.w = fmaf(w,bf_hi(q.y),acc0.w); den0 += w;
    }
    float denom = (den0+den1) + (den2+den3);
    float4 acc;
    acc.x = (acc0.x+acc1.x) + (acc2.x+acc3.x);
    acc.y = (acc0.y+acc1.y) + (acc2.y+acc3.y);
    acc.z = (acc0.z+acc1.z) + (acc2.z+acc3.z);
    acc.w = (acc0.w+acc1.w) + (acc2.w+acc3.w);
    float inv = 1.f / fmaxf(denom, 1e-9f);
    float4 b4 = *(const float4*)&bias[lane*4];
    s_out[wv][lane*4+0] = acc.x*inv + b4.x;
    s_out[wv][lane*4+1] = acc.y*inv + b4.y;
    s_out[wv][lane*4+2] = acc.z*inv + b4.z;
    s_out[wv][lane*4+3] = acc.w*inv + b4.w;
  }
  __syncthreads();
  if(valid && lane < 40){
    logits[(size_t)n*40 + lane] =
        0.25f * (s_out[wv][lane] + s_out[wv][40+lane] + s_out[wv][80+lane] + s_out[wv][120+lane]);
  }
}

extern "C" void kernel_launch(void* const* d_in, const int* in_sizes, int n_in,
                              void* d_out, int out_size, void* d_ws, size_t ws_size,
                              hipStream_t stream){
  const float* x   = (const float*)d_in[0];
  const int*   eix = (const int*)  d_in[1];
  const float* W0  = (const float*)d_in[2];
  const float* al0 = (const float*)d_in[3];
  const float* ar0 = (const float*)d_in[4];
  const float* b0  = (const float*)d_in[5];
  const float* W1  = (const float*)d_in[6];
  const float* al1 = (const float*)d_in[7];
  const float* ar1 = (const float*)d_in[8];
  const float* b1  = (const float*)d_in[9];
  const float* W2  = (const float*)d_in[10];
  const float* al2 = (const float*)d_in[11];
  const float* ar2 = (const float*)d_in[12];
  const float* b2  = (const float*)d_in[13];
  float* logits = (float*)d_out;

  const int N = in_sizes[0] / 256;   // 50000
  const int E = in_sizes[1] / 2;     // 800000
  const int* src = eix;
  const int* dst = eix + E;
  const int nb = (N + 1023) / 1024;

  char* ws = (char*)d_ws;
  auto alloc = [&](size_t bytes)->char*{
    char* p = ws; ws += (bytes + 255) & ~(size_t)255; return p;
  };
  int*   counts    = (int*)  alloc((size_t)N*4);
  int*   offsets   = (int*)  alloc((size_t)(N+1)*4);
  int*   cursor    = (int*)  alloc((size_t)N*4);
  int*   blocksums = (int*)  alloc((size_t)nb*4);
  int*   ssrc      = (int*)  alloc((size_t)E*4);
  int*   sdst      = (int*)  alloc((size_t)E*4);
  float* ew        = (float*)alloc((size_t)E*4*4);
  __hip_bfloat16* bufF = (__hip_bfloat16*)alloc((size_t)N*256*2);   // gemm output (bf16)
  ushortT* Hh      = (ushortT*)alloc((size_t)N*256*2);               // A hi plane (x / layer out)
  ushortT* Hl      = (ushortT*)alloc((size_t)N*256*2);               // A lo plane
  float* el_buf    = (float*)alloc((size_t)N*4*4);
  float* er_buf    = (float*)alloc((size_t)N*4*4);
  ushortT* Wth0 = (ushortT*)alloc(256*256*2);
  ushortT* Wtl0 = (ushortT*)alloc(256*256*2);
  ushortT* Wth1 = (ushortT*)alloc(256*256*2);
  ushortT* Wtl1 = (ushortT*)alloc(256*256*2);
  ushortT* Wth2 = (ushortT*)alloc(256*256*2);
  ushortT* Wtl2 = (ushortT*)alloc(256*256*2);

  // sort edges by dst (graph fixed across layers — one sort per call)
  hipMemsetAsync(counts, 0, (size_t)N*4, stream);
  hist_kernel   <<<(E+255)/256, 256, 0, stream>>>(dst, E, counts);
  scan1_kernel  <<<nb, 1024, 0, stream>>>(counts, N, offsets, blocksums);
  scan2_kernel  <<<1, 64, 0, stream>>>(blocksums, nb);
  scan3_kernel  <<<nb, 1024, 0, stream>>>(offsets, blocksums, N, E, cursor);
  scatter_kernel<<<(E+255)/256, 256, 0, stream>>>(src, dst, E, cursor, ssrc, sdst);

  // W pre-transpose + bf16 hi/lo split (tiny); x pre-split
  wsplit_kernel<<<256, 256, 0, stream>>>(W0, 256, Wth0, Wtl0);
  wsplit_kernel<<<256, 256, 0, stream>>>(W1, 256, Wth1, Wtl1);
  wsplit_kernel<<<256, 256, 0, stream>>>(W2, 160, Wth2, Wtl2);
  int total4 = N*64;
  xsplit_kernel<<<(total4+255)/256, 256, 0, stream>>>((const float4*)x, Hh, Hl, total4);

  dim3 gg(2, (N + 255)/256);       // 128-wide col tiles x 256-row blocks
  int aggGrid = (N+3)/4;
  int ewGrid  = (E+255)/256;
  // layer 0
  gemm_direct<<<gg, 256, 0, stream>>>(Hh, Hl, Wth0, Wtl0, (ushortT*)bufF, N, 256);
  attn_proj_bf<<<N, 256, 0, stream>>>(bufF, al0, ar0, el_buf, er_buf, 64);
  edge_w_kernel<<<ewGrid, 256, 0, stream>>>(ssrc, sdst, E, (const float4*)el_buf, (const float4*)er_buf, (float4*)ew);
  agg_kernel<<<aggGrid, 256, 0, stream>>>((const uint2*)bufF, ew, offsets, ssrc, b0, Hh, Hl, N);
  // layer 1
  gemm_direct<<<gg, 256, 0, stream>>>(Hh, Hl, Wth1, Wtl1, (ushortT*)bufF, N, 256);
  attn_proj_bf<<<N, 256, 0, stream>>>(bufF, al1, ar1, el_buf, er_buf, 64);
  edge_w_kernel<<<ewGrid, 256, 0, stream>>>(ssrc, sdst, E, (const float4*)el_buf, (const float4*)er_buf, (float4*)ew);
  agg_kernel<<<aggGrid, 256, 0, stream>>>((const uint2*)bufF, ew, offsets, ssrc, b1, Hh, Hl, N);
  // layer 2 (N=160; Wt rows padded with zeros, stores guarded)
  gemm_direct<<<gg, 256, 0, stream>>>(Hh, Hl, Wth2, Wtl2, (ushortT*)bufF, N, 160);
  attn_proj_bf<<<N, 256, 0, stream>>>(bufF, al2, ar2, el_buf, er_buf, 40);
  edge_w_kernel<<<ewGrid, 256, 0, stream>>>(ssrc, sdst, E, (const float4*)el_buf, (const float4*)er_buf, (float4*)ew);
  agg2_kernel<<<aggGrid, 256, 0, stream>>>((const uint2*)bufF, ew, offsets, ssrc, b2, logits, N);
}

// Round 8
// 574.573 us; speedup vs baseline: 1.1486x; 1.1486x over previous
//
#include <hip/hip_runtime.h>
#include <hip/hip_bf16.h>
#include <math.h>

#define NEG_SLOPE 0.2f

typedef unsigned short ushortT;
typedef __attribute__((ext_vector_type(8))) short short8;   // 8 bf16 = 4 VGPRs (MFMA A/B frag)
typedef __attribute__((ext_vector_type(4))) float f32x4;    // MFMA C/D frag

static __device__ __forceinline__ float leaky(float x){ return x > 0.f ? x : NEG_SLOPE * x; }
static __device__ __forceinline__ float elu(float x){ return x > 0.f ? x : (__expf(x) - 1.f); }

// bf16 helpers: RNE pack, exact unpack
static __device__ __forceinline__ ushortT f2bf(float f){
  unsigned u = __float_as_uint(f);
  u += 0x7fff + ((u >> 16) & 1);
  return (ushortT)(u >> 16);
}
static __device__ __forceinline__ float bf2f(ushortT h){ return __uint_as_float((unsigned)h << 16); }
static __device__ __forceinline__ float bf_lo(unsigned u){ return __uint_as_float(u << 16); }
static __device__ __forceinline__ float bf_hi(unsigned u){ return __uint_as_float(u & 0xffff0000u); }

// packed fragment-order layout for MFMA operands:
// elem (row, k) -> [ (rowtile*8 + t)*64 + quad*16 + row%16 ]*8 + k%8
//   rowtile=row/16, t=k/32, quad=(k%32)/8.  A wave frag load = contiguous 1KB.

// ---------------- edge sort by dst (counting sort) ----------------
__global__ void hist_kernel(const int* __restrict__ dst, int E, int* __restrict__ counts){
  int i = blockIdx.x*blockDim.x + threadIdx.x;
  if(i < E) atomicAdd(&counts[dst[i]], 1);
}

__global__ void scan1_kernel(const int* __restrict__ counts, int N,
                             int* __restrict__ offsets, int* __restrict__ blocksums){
  __shared__ int sdata[1024];
  int i = blockIdx.x*1024 + threadIdx.x;
  int v = (i<N) ? counts[i] : 0;
  sdata[threadIdx.x] = v;
  __syncthreads();
  for(int off=1; off<1024; off<<=1){
    int t = (threadIdx.x >= off) ? sdata[threadIdx.x-off] : 0;
    __syncthreads();
    sdata[threadIdx.x] += t;
    __syncthreads();
  }
  if(i<N) offsets[i] = sdata[threadIdx.x] - v;
  if(threadIdx.x==1023) blocksums[blockIdx.x] = sdata[1023];
}

__global__ void scan2_kernel(int* __restrict__ blocksums, int nb){
  __shared__ int sdata[64];
  int v = ((int)threadIdx.x < nb) ? blocksums[threadIdx.x] : 0;
  sdata[threadIdx.x] = v;
  __syncthreads();
  for(int off=1; off<64; off<<=1){
    int t = (threadIdx.x >= off) ? sdata[threadIdx.x-off] : 0;
    __syncthreads();
    sdata[threadIdx.x] += t;
    __syncthreads();
  }
  if((int)threadIdx.x < nb) blocksums[threadIdx.x] = sdata[threadIdx.x] - v;
}

__global__ void scan3_kernel(int* __restrict__ offsets, const int* __restrict__ blocksums,
                             int N, int E, int* __restrict__ cursor){
  int i = blockIdx.x*1024 + threadIdx.x;
  if(i < N){
    int o = offsets[i] + blocksums[blockIdx.x];
    offsets[i] = o;
    cursor[i] = o;
  }
  if(i == 0) offsets[N] = E;
}

__global__ void scatter_kernel(const int* __restrict__ src, const int* __restrict__ dst, int E,
                               int* __restrict__ cursor, int* __restrict__ ssrc,
                               int* __restrict__ sdst){
  int i = blockIdx.x*blockDim.x + threadIdx.x;
  if(i < E){
    int d = dst[i];
    int p = atomicAdd(&cursor[d], 1);
    ssrc[p] = src[i];
    sdst[p] = d;
  }
}

// ---------------- W split to packed fragment order: W[K=256, N] -> packed[16 ntiles] ----------------
// thread <-> (nt, t, lane); 8192 threads total
__global__ __launch_bounds__(256) void wsplit_pack(const float* __restrict__ W, int N,
                              ushortT* __restrict__ Wh, ushortT* __restrict__ Wl){
  int idx = blockIdx.x*256 + threadIdx.x;     // < 16*8*64 = 8192
  int lane = idx & 63;
  int t  = (idx >> 6) & 7;
  int nt = idx >> 9;
  int l15 = lane & 15, quad = lane >> 4;
  int n = nt*16 + l15;
  ushortT h[8], l[8];
  #pragma unroll
  for(int j=0;j<8;j++){
    int k = t*32 + quad*8 + j;
    float v = (n < N) ? W[(size_t)k*N + n] : 0.f;
    h[j] = f2bf(v);
    l[j] = f2bf(v - bf2f(h[j]));
  }
  *(short8*)&Wh[(size_t)idx*8] = *(short8*)h;
  *(short8*)&Wl[(size_t)idx*8] = *(short8*)l;
}

// ---------------- x split fp32 [M][256] -> packed hi/lo planes ----------------
__global__ __launch_bounds__(256) void xsplit_pack(const float* __restrict__ x, int M,
                              ushortT* __restrict__ Xh, ushortT* __restrict__ Xl, int total){
  int idx = blockIdx.x*256 + threadIdx.x;
  if(idx >= total) return;
  int lane = idx & 63;
  int t  = (idx >> 6) & 7;
  int mt = idx >> 9;
  int l15 = lane & 15, quad = lane >> 4;
  int m = mt*16 + l15;
  if(m >= M) return;
  const float* xr = &x[(size_t)m*256 + t*32 + quad*8];
  float4 v0 = *(const float4*)xr;
  float4 v1 = *(const float4*)(xr + 4);
  float vv[8] = {v0.x,v0.y,v0.z,v0.w,v1.x,v1.y,v1.z,v1.w};
  ushortT h[8], l[8];
  #pragma unroll
  for(int j=0;j<8;j++){
    h[j] = f2bf(vv[j]);
    l[j] = f2bf(vv[j] - bf2f(h[j]));
  }
  *(short8*)&Xh[(size_t)idx*8] = *(short8*)h;
  *(short8*)&Xl[(size_t)idx*8] = *(short8*)l;
}

// ---------------- bf16x3 MFMA GEMM from packed operands, LDS/barrier-free ----------------
// wave tile 32(M) x 64(N); block = 4 waves stacked in M (128 rows); K=256.
// If al != nullptr (layers 0/1): wave's 64-col tile == head h = blockIdx.x;
// fused el/er epilogue from pre-rounding fp32 accs.
__global__ __launch_bounds__(256) void gemm_packed(
    const ushortT* __restrict__ Ah, const ushortT* __restrict__ Al,
    const ushortT* __restrict__ Bh, const ushortT* __restrict__ Bl,
    ushortT* __restrict__ Cm, int M, int N,
    const float* __restrict__ al, const float* __restrict__ ar,
    float* __restrict__ el, float* __restrict__ er){
  const int lane = threadIdx.x & 63;
  const int wv   = threadIdx.x >> 6;
  const int l15  = lane & 15, quad = lane >> 4;
  const int m0   = blockIdx.y*128 + wv*32;
  const int n0   = blockIdx.x*64;
  const int mt0  = m0 >> 4;     // 2 mtiles per wave
  const int nt0  = n0 >> 4;     // 4 ntiles per wave

  f32x4 acc[2][4];
  #pragma unroll
  for(int i=0;i<2;i++)
    #pragma unroll
    for(int j=0;j<4;j++){ acc[i][j][0]=0.f; acc[i][j][1]=0.f; acc[i][j][2]=0.f; acc[i][j][3]=0.f; }

  #pragma unroll
  for(int t=0; t<8; t++){
    short8 a_h[2], a_l[2], b_h[4], b_l[4];
    #pragma unroll
    for(int i=0;i<2;i++){
      size_t ad = (((size_t)(mt0+i)*8 + t)*64 + lane)*8;
      a_h[i] = *(const short8*)&Ah[ad];
      a_l[i] = *(const short8*)&Al[ad];
    }
    #pragma unroll
    for(int j=0;j<4;j++){
      size_t bd = (((size_t)(nt0+j)*8 + t)*64 + lane)*8;
      b_h[j] = *(const short8*)&Bh[bd];
      b_l[j] = *(const short8*)&Bl[bd];
    }
    #pragma unroll
    for(int i=0;i<2;i++)
      #pragma unroll
      for(int j=0;j<4;j++){
        acc[i][j] = __builtin_amdgcn_mfma_f32_16x16x32_bf16(a_h[i], b_h[j], acc[i][j], 0,0,0);
        acc[i][j] = __builtin_amdgcn_mfma_f32_16x16x32_bf16(a_h[i], b_l[j], acc[i][j], 0,0,0);
        acc[i][j] = __builtin_amdgcn_mfma_f32_16x16x32_bf16(a_l[i], b_h[j], acc[i][j], 0,0,0);
      }
  }

  // fused el/er (layers 0/1): this col-tile is exactly head h
  if(al){
    const int h = blockIdx.x;
    float alv[4], arv[4];
    #pragma unroll
    for(int j=0;j<4;j++){
      alv[j] = al[h*64 + j*16 + l15];
      arv[j] = ar[h*64 + j*16 + l15];
    }
    #pragma unroll
    for(int i=0;i<2;i++){
      #pragma unroll
      for(int r=0;r<4;r++){
        float pl = acc[i][0][r]*alv[0] + acc[i][1][r]*alv[1]
                 + acc[i][2][r]*alv[2] + acc[i][3][r]*alv[3];
        float pr = acc[i][0][r]*arv[0] + acc[i][1][r]*arv[1]
                 + acc[i][2][r]*arv[2] + acc[i][3][r]*arv[3];
        #pragma unroll
        for(int off=1; off<16; off<<=1){ pl += __shfl_xor(pl,off); pr += __shfl_xor(pr,off); }
        int gm = m0 + i*16 + quad*4 + r;
        if(l15==0 && gm < M){ el[gm*4+h] = pl; er[gm*4+h] = pr; }
      }
    }
  }

  // C store, row-major bf16.  C/D layout: col=lane&15, row=quad*4+r
  #pragma unroll
  for(int i=0;i<2;i++){
    #pragma unroll
    for(int r=0;r<4;r++){
      int gm = m0 + i*16 + quad*4 + r;
      if(gm >= M) continue;
      #pragma unroll
      for(int j=0;j<4;j++){
        int gn = n0 + j*16 + l15;
        if(gn < N) Cm[(size_t)gm*N + gn] = f2bf(acc[i][j][r]);
      }
    }
  }
}

// ---------------- el/er projection from bf16 feat (layer 2 only) ----------------
__global__ void attn_proj_bf(const __hip_bfloat16* __restrict__ feat, const float* __restrict__ a_l,
                             const float* __restrict__ a_r, float* __restrict__ el,
                             float* __restrict__ er, int D){
  int n = blockIdx.x;
  int h = threadIdx.x >> 6;
  int lane = threadIdx.x & 63;
  float vl = 0.f, vr = 0.f;
  for(int d=lane; d<D; d+=64){
    float f = (float)feat[(size_t)n*4*D + h*D + d];
    vl = fmaf(f, a_l[h*D+d], vl);
    vr = fmaf(f, a_r[h*D+d], vr);
  }
  #pragma unroll
  for(int off=32; off; off>>=1){ vl += __shfl_down(vl,off); vr += __shfl_down(vr,off); }
  if(lane==0){ el[n*4+h] = vl; er[n*4+h] = vr; }
}

// ---------------- per-edge softmax numerators (all 4 heads) ----------------
__global__ __launch_bounds__(256) void edge_w_kernel(const int* __restrict__ ssrc,
                              const int* __restrict__ sdst, int E,
                              const float4* __restrict__ el4, const float4* __restrict__ er4,
                              float4* __restrict__ ew){
  int e = blockIdx.x*blockDim.x + threadIdx.x;
  if(e >= E) return;
  int s = ssrc[e], d = sdst[e];
  float4 l = el4[s], r = er4[d];
  float4 w;
  w.x = __expf(leaky(l.x + r.x));
  w.y = __expf(leaky(l.y + r.y));
  w.z = __expf(leaky(l.z + r.z));
  w.w = __expf(leaky(l.w + r.w));
  ew[e] = w;
}

// ---------------- softmax + aggregate, layers 0/1 (H*D=256 bf16), ELU ----------------
// one WAVE per dst node; epilogue writes next-layer A in PACKED hi/lo fragment order
__global__ __launch_bounds__(256) void agg_kernel(const uint2* __restrict__ feat2,
                           const float* __restrict__ ew,
                           const int* __restrict__ offsets, const int* __restrict__ ssrc,
                           const float* __restrict__ bias,
                           ushortT* __restrict__ Hh, ushortT* __restrict__ Hl, int N){
  int wv = threadIdx.x >> 6;
  int lane = threadIdx.x & 63;
  int n = blockIdx.x*4 + wv;
  if(n >= N) return;
  int h = lane >> 4;
  int e0 = offsets[n], e1 = offsets[n+1];
  float4 acc0 = make_float4(0.f,0.f,0.f,0.f), acc1 = acc0, acc2 = acc0, acc3 = acc0;
  float den0 = 0.f, den1 = 0.f, den2 = 0.f, den3 = 0.f;
  int e = e0;
  for(; e+3 < e1; e += 4){
    int s0 = ssrc[e], s1 = ssrc[e+1], s2 = ssrc[e+2], s3 = ssrc[e+3];
    float w0 = ew[(size_t)e*4 + h];
    float w1 = ew[(size_t)(e+1)*4 + h];
    float w2 = ew[(size_t)(e+2)*4 + h];
    float w3 = ew[(size_t)(e+3)*4 + h];
    uint2 q0 = feat2[(size_t)s0*64 + lane];
    uint2 q1 = feat2[(size_t)s1*64 + lane];
    uint2 q2 = feat2[(size_t)s2*64 + lane];
    uint2 q3 = feat2[(size_t)s3*64 + lane];
    acc0.x = fmaf(w0,bf_lo(q0.x),acc0.x); acc0.y = fmaf(w0,bf_hi(q0.x),acc0.y);
    acc0.z = fmaf(w0,bf_lo(q0.y),acc0.z); acc0.w = fmaf(w0,bf_hi(q0.y),acc0.w); den0 += w0;
    acc1.x = fmaf(w1,bf_lo(q1.x),acc1.x); acc1.y = fmaf(w1,bf_hi(q1.x),acc1.y);
    acc1.z = fmaf(w1,bf_lo(q1.y),acc1.z); acc1.w = fmaf(w1,bf_hi(q1.y),acc1.w); den1 += w1;
    acc2.x = fmaf(w2,bf_lo(q2.x),acc2.x); acc2.y = fmaf(w2,bf_hi(q2.x),acc2.y);
    acc2.z = fmaf(w2,bf_lo(q2.y),acc2.z); acc2.w = fmaf(w2,bf_hi(q2.y),acc2.w); den2 += w2;
    acc3.x = fmaf(w3,bf_lo(q3.x),acc3.x); acc3.y = fmaf(w3,bf_hi(q3.x),acc3.y);
    acc3.z = fmaf(w3,bf_lo(q3.y),acc3.z); acc3.w = fmaf(w3,bf_hi(q3.y),acc3.w); den3 += w3;
  }
  for(; e < e1; e++){
    int s = ssrc[e];
    float w = ew[(size_t)e*4 + h];
    uint2 q = feat2[(size_t)s*64 + lane];
    acc0.x = fmaf(w,bf_lo(q.x),acc0.x); acc0.y = fmaf(w,bf_hi(q.x),acc0.y);
    acc0.z = fmaf(w,bf_lo(q.y),acc0.z); acc0.w = fmaf(w,bf_hi(q.y),acc0.w); den0 += w;
  }
  float denom = (den0+den1) + (den2+den3);
  float4 acc;
  acc.x = (acc0.x+acc1.x) + (acc2.x+acc3.x);
  acc.y = (acc0.y+acc1.y) + (acc2.y+acc3.y);
  acc.z = (acc0.z+acc1.z) + (acc2.z+acc3.z);
  acc.w = (acc0.w+acc1.w) + (acc2.w+acc3.w);
  float inv = 1.f / fmaxf(denom, 1e-9f);
  float4 b4 = *(const float4*)&bias[lane*4];
  float o0 = elu(acc.x*inv + b4.x);
  float o1 = elu(acc.y*inv + b4.y);
  float o2 = elu(acc.z*inv + b4.z);
  float o3 = elu(acc.w*inv + b4.w);
  ushortT h0=f2bf(o0), h1=f2bf(o1), h2=f2bf(o2), h3=f2bf(o3);
  ushort4 hv = make_ushort4(h0,h1,h2,h3);
  ushort4 lv = make_ushort4(f2bf(o0-bf2f(h0)), f2bf(o1-bf2f(h1)),
                            f2bf(o2-bf2f(h2)), f2bf(o3-bf2f(h3)));
  // packed-store: node n holds row n; lane owns k = lane*4 .. lane*4+3
  int mtile = n >> 4, l15n = n & 15;
  int t = lane >> 3;
  int quadk = (lane & 7) >> 1;
  int rem = (lane & 1) * 4;
  size_t ad = (((size_t)(mtile*8 + t))*64 + quadk*16 + l15n)*8 + rem;
  *(ushort4*)&Hh[ad] = hv;
  *(ushort4*)&Hl[ad] = lv;
}

// ---------------- layer 2: aggregate (H*C=160 bf16) + head-mean logits ----------------
__global__ __launch_bounds__(256) void agg2_kernel(const uint2* __restrict__ feat2,
                            const float* __restrict__ ew,
                            const int* __restrict__ offsets, const int* __restrict__ ssrc,
                            const float* __restrict__ bias, float* __restrict__ logits, int N){
  __shared__ float s_out[4][160];
  int wv = threadIdx.x >> 6;
  int lane = threadIdx.x & 63;
  int n = blockIdx.x*4 + wv;
  bool valid = (n < N);
  if(valid && lane < 40){
    int h = lane / 10;
    int e0 = offsets[n], e1 = offsets[n+1];
    float4 acc0 = make_float4(0.f,0.f,0.f,0.f), acc1 = acc0, acc2 = acc0, acc3 = acc0;
    float den0 = 0.f, den1 = 0.f, den2 = 0.f, den3 = 0.f;
    int e = e0;
    for(; e+3 < e1; e += 4){
      int s0 = ssrc[e], s1 = ssrc[e+1], s2 = ssrc[e+2], s3 = ssrc[e+3];
      float w0 = ew[(size_t)e*4 + h];
      float w1 = ew[(size_t)(e+1)*4 + h];
      float w2 = ew[(size_t)(e+2)*4 + h];
      float w3 = ew[(size_t)(e+3)*4 + h];
      uint2 q0 = feat2[(size_t)s0*40 + lane];
      uint2 q1 = feat2[(size_t)s1*40 + lane];
      uint2 q2 = feat2[(size_t)s2*40 + lane];
      uint2 q3 = feat2[(size_t)s3*40 + lane];
      acc0.x = fmaf(w0,bf_lo(q0.x),acc0.x); acc0.y = fmaf(w0,bf_hi(q0.x),acc0.y);
      acc0.z = fmaf(w0,bf_lo(q0.y),acc0.z); acc0.w = fmaf(w0,bf_hi(q0.y),acc0.w); den0 += w0;
      acc1.x = fmaf(w1,bf_lo(q1.x),acc1.x); acc1.y = fmaf(w1,bf_hi(q1.x),acc1.y);
      acc1.z = fmaf(w1,bf_lo(q1.y),acc1.z); acc1.w = fmaf(w1,bf_hi(q1.y),acc1.w); den1 += w1;
      acc2.x = fmaf(w2,bf_lo(q2.x),acc2.x); acc2.y = fmaf(w2,bf_hi(q2.x),acc2.y);
      acc2.z = fmaf(w2,bf_lo(q2.y),acc2.z); acc2.w = fmaf(w2,bf_hi(q2.y),acc2.w); den2 += w2;
      acc3.x = fmaf(w3,bf_lo(q3.x),acc3.x); acc3.y = fmaf(w3,bf_hi(q3.x),acc3.y);
      acc3.z = fmaf(w3,bf_lo(q3.y),acc3.z); acc3.w = fmaf(w3,bf_hi(q3.y),acc3.w); den3 += w3;
    }
    for(; e < e1; e++){
      int s = ssrc[e];
      float w = ew[(size_t)e*4 + h];
      uint2 q = feat2[(size_t)s*40 + lane];
      acc0.x = fmaf(w,bf_lo(q.x),acc0.x); acc0.y = fmaf(w,bf_hi(q.x),acc0.y);
      acc0.z = fmaf(w,bf_lo(q.y),acc0.z); acc0.w = fmaf(w,bf_hi(q.y),acc0.w); den0 += w;
    }
    float denom = (den0+den1) + (den2+den3);
    float4 acc;
    acc.x = (acc0.x+acc1.x) + (acc2.x+acc3.x);
    acc.y = (acc0.y+acc1.y) + (acc2.y+acc3.y);
    acc.z = (acc0.z+acc1.z) + (acc2.z+acc3.z);
    acc.w = (acc0.w+acc1.w) + (acc2.w+acc3.w);
    float inv = 1.f / fmaxf(denom, 1e-9f);
    float4 b4 = *(const float4*)&bias[lane*4];
    s_out[wv][lane*4+0] = acc.x*inv + b4.x;
    s_out[wv][lane*4+1] = acc.y*inv + b4.y;
    s_out[wv][lane*4+2] = acc.z*inv + b4.z;
    s_out[wv][lane*4+3] = acc.w*inv + b4.w;
  }
  __syncthreads();
  if(valid && lane < 40){
    logits[(size_t)n*40 + lane] =
        0.25f * (s_out[wv][lane] + s_out[wv][40+lane] + s_out[wv][80+lane] + s_out[wv][120+lane]);
  }
}

extern "C" void kernel_launch(void* const* d_in, const int* in_sizes, int n_in,
                              void* d_out, int out_size, void* d_ws, size_t ws_size,
                              hipStream_t stream){
  const float* x   = (const float*)d_in[0];
  const int*   eix = (const int*)  d_in[1];
  const float* W0  = (const float*)d_in[2];
  const float* al0 = (const float*)d_in[3];
  const float* ar0 = (const float*)d_in[4];
  const float* b0  = (const float*)d_in[5];
  const float* W1  = (const float*)d_in[6];
  const float* al1 = (const float*)d_in[7];
  const float* ar1 = (const float*)d_in[8];
  const float* b1  = (const float*)d_in[9];
  const float* W2  = (const float*)d_in[10];
  const float* al2 = (const float*)d_in[11];
  const float* ar2 = (const float*)d_in[12];
  const float* b2  = (const float*)d_in[13];
  float* logits = (float*)d_out;

  const int N = in_sizes[0] / 256;   // 50000
  const int E = in_sizes[1] / 2;     // 800000
  const int* src = eix;
  const int* dst = eix + E;
  const int nb = (N + 1023) / 1024;

  char* ws = (char*)d_ws;
  auto alloc = [&](size_t bytes)->char*{
    char* p = ws; ws += (bytes + 255) & ~(size_t)255; return p;
  };
  const int nblocksM = (N + 127)/128;          // gemm M-blocks
  const size_t apackElems = (size_t)nblocksM * 8 /*mtiles*/ * 8 /*t*/ * 64 * 8;
  int*   counts    = (int*)  alloc((size_t)N*4);
  int*   offsets   = (int*)  alloc((size_t)(N+1)*4);
  int*   cursor    = (int*)  alloc((size_t)N*4);
  int*   blocksums = (int*)  alloc((size_t)nb*4);
  int*   ssrc      = (int*)  alloc((size_t)E*4);
  int*   sdst      = (int*)  alloc((size_t)E*4);
  float* ew        = (float*)alloc((size_t)E*4*4);
  __hip_bfloat16* bufF = (__hip_bfloat16*)alloc((size_t)N*256*2);   // gemm output (bf16, row-major)
  ushortT* Hh      = (ushortT*)alloc(apackElems*2);                  // packed A hi plane
  ushortT* Hl      = (ushortT*)alloc(apackElems*2);                  // packed A lo plane
  float* el_buf    = (float*)alloc((size_t)N*4*4);
  float* er_buf    = (float*)alloc((size_t)N*4*4);
  ushortT* Wph0 = (ushortT*)alloc(16*8*64*8*2);
  ushortT* Wpl0 = (ushortT*)alloc(16*8*64*8*2);
  ushortT* Wph1 = (ushortT*)alloc(16*8*64*8*2);
  ushortT* Wpl1 = (ushortT*)alloc(16*8*64*8*2);
  ushortT* Wph2 = (ushortT*)alloc(16*8*64*8*2);
  ushortT* Wpl2 = (ushortT*)alloc(16*8*64*8*2);

  // sort edges by dst (graph fixed across layers — one sort per call)
  hipMemsetAsync(counts, 0, (size_t)N*4, stream);
  hist_kernel   <<<(E+255)/256, 256, 0, stream>>>(dst, E, counts);
  scan1_kernel  <<<nb, 1024, 0, stream>>>(counts, N, offsets, blocksums);
  scan2_kernel  <<<1, 64, 0, stream>>>(blocksums, nb);
  scan3_kernel  <<<nb, 1024, 0, stream>>>(offsets, blocksums, N, E, cursor);
  scatter_kernel<<<(E+255)/256, 256, 0, stream>>>(src, dst, E, cursor, ssrc, sdst);

  // weight + x packing (fragment order, hi/lo split)
  wsplit_pack<<<32, 256, 0, stream>>>(W0, 256, Wph0, Wpl0);
  wsplit_pack<<<32, 256, 0, stream>>>(W1, 256, Wph1, Wpl1);
  wsplit_pack<<<32, 256, 0, stream>>>(W2, 160, Wph2, Wpl2);
  int xtotal = ((N + 15)/16) * 8 * 64;
  xsplit_pack<<<(xtotal+255)/256, 256, 0, stream>>>(x, N, Hh, Hl, xtotal);

  dim3 gg01(4, nblocksM);          // layers 0/1: 4 col-tiles of 64 (= heads)
  dim3 gg2 (3, nblocksM);          // layer 2: 160 cols -> 3 col-tiles (guarded)
  int aggGrid = (N+3)/4;
  int ewGrid  = (E+255)/256;
  // layer 0 (el/er fused in gemm epilogue)
  gemm_packed<<<gg01, 256, 0, stream>>>(Hh, Hl, Wph0, Wpl0, (ushortT*)bufF, N, 256, al0, ar0, el_buf, er_buf);
  edge_w_kernel<<<ewGrid, 256, 0, stream>>>(ssrc, sdst, E, (const float4*)el_buf, (const float4*)er_buf, (float4*)ew);
  agg_kernel<<<aggGrid, 256, 0, stream>>>((const uint2*)bufF, ew, offsets, ssrc, b0, Hh, Hl, N);
  // layer 1
  gemm_packed<<<gg01, 256, 0, stream>>>(Hh, Hl, Wph1, Wpl1, (ushortT*)bufF, N, 256, al1, ar1, el_buf, er_buf);
  edge_w_kernel<<<ewGrid, 256, 0, stream>>>(ssrc, sdst, E, (const float4*)el_buf, (const float4*)er_buf, (float4*)ew);
  agg_kernel<<<aggGrid, 256, 0, stream>>>((const uint2*)bufF, ew, offsets, ssrc, b1, Hh, Hl, N);
  // layer 2 (heads are 40-wide — separate attn_proj on bf16 feat)
  gemm_packed<<<gg2, 256, 0, stream>>>(Hh, Hl, Wph2, Wpl2, (ushortT*)bufF, N, 160, nullptr, nullptr, nullptr, nullptr);
  attn_proj_bf<<<N, 256, 0, stream>>>(bufF, al2, ar2, el_buf, er_buf, 40);
  edge_w_kernel<<<ewGrid, 256, 0, stream>>>(ssrc, sdst, E, (const float4*)el_buf, (const float4*)er_buf, (float4*)ew);
  agg2_kernel<<<aggGrid, 256, 0, stream>>>((const uint2*)bufF, ew, offsets, ssrc, b2, logits, N);
}

// Round 9
// 569.868 us; speedup vs baseline: 1.1581x; 1.0083x over previous
//
#include <hip/hip_runtime.h>
#include <hip/hip_bf16.h>
#include <math.h>

#define NEG_SLOPE 0.2f

typedef unsigned short ushortT;
typedef __attribute__((ext_vector_type(8))) short short8;   // 8 bf16 = 4 VGPRs (MFMA A/B frag)
typedef __attribute__((ext_vector_type(4))) float f32x4;    // MFMA C/D frag

static __device__ __forceinline__ float leaky(float x){ return x > 0.f ? x : NEG_SLOPE * x; }
static __device__ __forceinline__ float elu(float x){ return x > 0.f ? x : (__expf(x) - 1.f); }

// bf16 helpers: RNE pack, exact unpack
static __device__ __forceinline__ ushortT f2bf(float f){
  unsigned u = __float_as_uint(f);
  u += 0x7fff + ((u >> 16) & 1);
  return (ushortT)(u >> 16);
}
static __device__ __forceinline__ float bf2f(ushortT h){ return __uint_as_float((unsigned)h << 16); }
static __device__ __forceinline__ float bf_lo(unsigned u){ return __uint_as_float(u << 16); }
static __device__ __forceinline__ float bf_hi(unsigned u){ return __uint_as_float(u & 0xffff0000u); }

// A-plane layout (both GEMM-frag-loadable and line-contiguous for agg stores):
//   elem (row, k) -> [ (k/32)*Mpad + row ]*32 + k%32
// GEMM frag: lane reads 16B at ((t*Mpad + row)*32 + quad*8); wave = 16 full lines.
// agg store: node row writes 8 full 64B lines (one per t). Zero RMW.
// B-plane (weights) layout: [(ntile*8 + t)*64 + lane]*8  (contiguous 1KB per frag).

// ---------------- edge sort by dst (counting sort) ----------------
__global__ void hist_kernel(const int* __restrict__ dst, int E, int* __restrict__ counts){
  int i = blockIdx.x*blockDim.x + threadIdx.x;
  if(i < E) atomicAdd(&counts[dst[i]], 1);
}

__global__ void scan1_kernel(const int* __restrict__ counts, int N,
                             int* __restrict__ offsets, int* __restrict__ blocksums){
  __shared__ int sdata[1024];
  int i = blockIdx.x*1024 + threadIdx.x;
  int v = (i<N) ? counts[i] : 0;
  sdata[threadIdx.x] = v;
  __syncthreads();
  for(int off=1; off<1024; off<<=1){
    int t = (threadIdx.x >= off) ? sdata[threadIdx.x-off] : 0;
    __syncthreads();
    sdata[threadIdx.x] += t;
    __syncthreads();
  }
  if(i<N) offsets[i] = sdata[threadIdx.x] - v;
  if(threadIdx.x==1023) blocksums[blockIdx.x] = sdata[1023];
}

__global__ void scan2_kernel(int* __restrict__ blocksums, int nb){
  __shared__ int sdata[64];
  int v = ((int)threadIdx.x < nb) ? blocksums[threadIdx.x] : 0;
  sdata[threadIdx.x] = v;
  __syncthreads();
  for(int off=1; off<64; off<<=1){
    int t = (threadIdx.x >= off) ? sdata[threadIdx.x-off] : 0;
    __syncthreads();
    sdata[threadIdx.x] += t;
    __syncthreads();
  }
  if((int)threadIdx.x < nb) blocksums[threadIdx.x] = sdata[threadIdx.x] - v;
}

__global__ void scan3_kernel(int* __restrict__ offsets, const int* __restrict__ blocksums,
                             int N, int E, int* __restrict__ cursor){
  int i = blockIdx.x*1024 + threadIdx.x;
  if(i < N){
    int o = offsets[i] + blocksums[blockIdx.x];
    offsets[i] = o;
    cursor[i] = o;
  }
  if(i == 0) offsets[N] = E;
}

__global__ void scatter_kernel(const int* __restrict__ src, const int* __restrict__ dst, int E,
                               int* __restrict__ cursor, int* __restrict__ ssrc,
                               int* __restrict__ sdst){
  int i = blockIdx.x*blockDim.x + threadIdx.x;
  if(i < E){
    int d = dst[i];
    int p = atomicAdd(&cursor[d], 1);
    ssrc[p] = src[i];
    sdst[p] = d;
  }
}

// ---------------- W split to packed fragment order: W[K=256, N] -> packed[16 ntiles] ----------------
__global__ __launch_bounds__(256) void wsplit_pack(const float* __restrict__ W, int N,
                              ushortT* __restrict__ Wh, ushortT* __restrict__ Wl){
  int idx = blockIdx.x*256 + threadIdx.x;     // < 16*8*64 = 8192
  int lane = idx & 63;
  int t  = (idx >> 6) & 7;
  int nt = idx >> 9;
  int l15 = lane & 15, quad = lane >> 4;
  int n = nt*16 + l15;
  ushortT h[8], l[8];
  #pragma unroll
  for(int j=0;j<8;j++){
    int k = t*32 + quad*8 + j;
    float v = (n < N) ? W[(size_t)k*N + n] : 0.f;
    h[j] = f2bf(v);
    l[j] = f2bf(v - bf2f(h[j]));
  }
  *(short8*)&Wh[(size_t)idx*8] = *(short8*)h;
  *(short8*)&Wl[(size_t)idx*8] = *(short8*)l;
}

// ---------------- x split fp32 [M][256] -> A-plane layout [t][Mpad][32] ----------------
// thread = (t, row); writes 64B contiguous per plane; pad rows zeroed (stay zero forever).
__global__ __launch_bounds__(256) void xsplit_pack(const float* __restrict__ x, int M, int Mpad,
                              ushortT* __restrict__ Xh, ushortT* __restrict__ Xl){
  int idx = blockIdx.x*256 + threadIdx.x;     // over 8*Mpad, idx = t*Mpad + m
  if(idx >= 8*Mpad) return;
  int t = idx / Mpad, m = idx - t*Mpad;
  size_t base = (size_t)idx * 32;
  if(m < M){
    const float* xr = &x[(size_t)m*256 + t*32];
    #pragma unroll
    for(int c=0;c<4;c++){
      float4 v0 = *(const float4*)&xr[c*8];
      float4 v1 = *(const float4*)&xr[c*8+4];
      float vv[8] = {v0.x,v0.y,v0.z,v0.w,v1.x,v1.y,v1.z,v1.w};
      ushortT h[8], l[8];
      #pragma unroll
      for(int j=0;j<8;j++){
        h[j] = f2bf(vv[j]);
        l[j] = f2bf(vv[j] - bf2f(h[j]));
      }
      *(short8*)&Xh[base + c*8] = *(short8*)h;
      *(short8*)&Xl[base + c*8] = *(short8*)l;
    }
  } else {
    short8 z = {0,0,0,0,0,0,0,0};
    #pragma unroll
    for(int c=0;c<4;c++){ *(short8*)&Xh[base + c*8] = z; *(short8*)&Xl[base + c*8] = z; }
  }
}

// ---------------- bf16x3 MFMA GEMM from packed operands, LDS/barrier-free ----------------
// wave tile 32(M) x 64(N); block = 4 waves stacked in M (128 rows); K=256.
// If al != nullptr (layers 0/1): wave's 64-col tile == head h = blockIdx.x;
// fused el/er epilogue from pre-rounding fp32 accs.
__global__ __launch_bounds__(256) void gemm_packed(
    const ushortT* __restrict__ Ah, const ushortT* __restrict__ Al,
    const ushortT* __restrict__ Bh, const ushortT* __restrict__ Bl,
    ushortT* __restrict__ Cm, int M, int Mpad, int N,
    const float* __restrict__ al, const float* __restrict__ ar,
    float* __restrict__ el, float* __restrict__ er){
  const int lane = threadIdx.x & 63;
  const int wv   = threadIdx.x >> 6;
  const int l15  = lane & 15, quad = lane >> 4;
  const int m0   = blockIdx.y*128 + wv*32;
  const int n0   = blockIdx.x*64;
  const int nt0  = n0 >> 4;     // 4 ntiles per wave

  f32x4 acc[2][4];
  #pragma unroll
  for(int i=0;i<2;i++)
    #pragma unroll
    for(int j=0;j<4;j++){ acc[i][j][0]=0.f; acc[i][j][1]=0.f; acc[i][j][2]=0.f; acc[i][j][3]=0.f; }

  #pragma unroll
  for(int t=0; t<8; t++){
    short8 a_h[2], a_l[2], b_h[4], b_l[4];
    #pragma unroll
    for(int i=0;i<2;i++){
      size_t ad = ((size_t)t*Mpad + (m0 + i*16 + l15))*32 + quad*8;
      a_h[i] = *(const short8*)&Ah[ad];
      a_l[i] = *(const short8*)&Al[ad];
    }
    #pragma unroll
    for(int j=0;j<4;j++){
      size_t bd = (((size_t)(nt0+j)*8 + t)*64 + lane)*8;
      b_h[j] = *(const short8*)&Bh[bd];
      b_l[j] = *(const short8*)&Bl[bd];
    }
    #pragma unroll
    for(int i=0;i<2;i++)
      #pragma unroll
      for(int j=0;j<4;j++){
        acc[i][j] = __builtin_amdgcn_mfma_f32_16x16x32_bf16(a_h[i], b_h[j], acc[i][j], 0,0,0);
        acc[i][j] = __builtin_amdgcn_mfma_f32_16x16x32_bf16(a_h[i], b_l[j], acc[i][j], 0,0,0);
        acc[i][j] = __builtin_amdgcn_mfma_f32_16x16x32_bf16(a_l[i], b_h[j], acc[i][j], 0,0,0);
      }
  }

  // fused el/er (layers 0/1): this col-tile is exactly head h
  if(al){
    const int h = blockIdx.x;
    float alv[4], arv[4];
    #pragma unroll
    for(int j=0;j<4;j++){
      alv[j] = al[h*64 + j*16 + l15];
      arv[j] = ar[h*64 + j*16 + l15];
    }
    #pragma unroll
    for(int i=0;i<2;i++){
      #pragma unroll
      for(int r=0;r<4;r++){
        float pl = acc[i][0][r]*alv[0] + acc[i][1][r]*alv[1]
                 + acc[i][2][r]*alv[2] + acc[i][3][r]*alv[3];
        float pr = acc[i][0][r]*arv[0] + acc[i][1][r]*arv[1]
                 + acc[i][2][r]*arv[2] + acc[i][3][r]*arv[3];
        #pragma unroll
        for(int off=1; off<16; off<<=1){ pl += __shfl_xor(pl,off); pr += __shfl_xor(pr,off); }
        int gm = m0 + i*16 + quad*4 + r;
        if(l15==0 && gm < M){ el[gm*4+h] = pl; er[gm*4+h] = pr; }
      }
    }
  }

  // C store, row-major bf16.  C/D layout: col=lane&15, row=quad*4+r
  #pragma unroll
  for(int i=0;i<2;i++){
    #pragma unroll
    for(int r=0;r<4;r++){
      int gm = m0 + i*16 + quad*4 + r;
      if(gm >= M) continue;
      #pragma unroll
      for(int j=0;j<4;j++){
        int gn = n0 + j*16 + l15;
        if(gn < N) Cm[(size_t)gm*N + gn] = f2bf(acc[i][j][r]);
      }
    }
  }
}

// ---------------- el/er projection from bf16 feat (layer 2 only) ----------------
__global__ void attn_proj_bf(const __hip_bfloat16* __restrict__ feat, const float* __restrict__ a_l,
                             const float* __restrict__ a_r, float* __restrict__ el,
                             float* __restrict__ er, int D){
  int n = blockIdx.x;
  int h = threadIdx.x >> 6;
  int lane = threadIdx.x & 63;
  float vl = 0.f, vr = 0.f;
  for(int d=lane; d<D; d+=64){
    float f = (float)feat[(size_t)n*4*D + h*D + d];
    vl = fmaf(f, a_l[h*D+d], vl);
    vr = fmaf(f, a_r[h*D+d], vr);
  }
  #pragma unroll
  for(int off=32; off; off>>=1){ vl += __shfl_down(vl,off); vr += __shfl_down(vr,off); }
  if(lane==0){ el[n*4+h] = vl; er[n*4+h] = vr; }
}

// ---------------- per-edge softmax numerators (all 4 heads) ----------------
__global__ __launch_bounds__(256) void edge_w_kernel(const int* __restrict__ ssrc,
                              const int* __restrict__ sdst, int E,
                              const float4* __restrict__ el4, const float4* __restrict__ er4,
                              float4* __restrict__ ew){
  int e = blockIdx.x*blockDim.x + threadIdx.x;
  if(e >= E) return;
  int s = ssrc[e], d = sdst[e];
  float4 l = el4[s], r = er4[d];
  float4 w;
  w.x = __expf(leaky(l.x + r.x));
  w.y = __expf(leaky(l.y + r.y));
  w.z = __expf(leaky(l.z + r.z));
  w.w = __expf(leaky(l.w + r.w));
  ew[e] = w;
}

// ---------------- softmax + aggregate, layers 0/1 (H*D=256 bf16), ELU ----------------
// one WAVE per dst node; epilogue writes next-layer A planes in [t][Mpad][32] layout:
// node n writes 8 full 64B lines per plane (zero RMW).
__global__ __launch_bounds__(256) void agg_kernel(const uint2* __restrict__ feat2,
                           const float* __restrict__ ew,
                           const int* __restrict__ offsets, const int* __restrict__ ssrc,
                           const float* __restrict__ bias,
                           ushortT* __restrict__ Hh, ushortT* __restrict__ Hl, int N, int Mpad){
  int wv = threadIdx.x >> 6;
  int lane = threadIdx.x & 63;
  int n = blockIdx.x*4 + wv;
  if(n >= N) return;
  int h = lane >> 4;
  int e0 = offsets[n], e1 = offsets[n+1];
  float4 acc0 = make_float4(0.f,0.f,0.f,0.f), acc1 = acc0, acc2 = acc0, acc3 = acc0;
  float den0 = 0.f, den1 = 0.f, den2 = 0.f, den3 = 0.f;
  int e = e0;
  for(; e+3 < e1; e += 4){
    int s0 = ssrc[e], s1 = ssrc[e+1], s2 = ssrc[e+2], s3 = ssrc[e+3];
    float w0 = ew[(size_t)e*4 + h];
    float w1 = ew[(size_t)(e+1)*4 + h];
    float w2 = ew[(size_t)(e+2)*4 + h];
    float w3 = ew[(size_t)(e+3)*4 + h];
    uint2 q0 = feat2[(size_t)s0*64 + lane];
    uint2 q1 = feat2[(size_t)s1*64 + lane];
    uint2 q2 = feat2[(size_t)s2*64 + lane];
    uint2 q3 = feat2[(size_t)s3*64 + lane];
    acc0.x = fmaf(w0,bf_lo(q0.x),acc0.x); acc0.y = fmaf(w0,bf_hi(q0.x),acc0.y);
    acc0.z = fmaf(w0,bf_lo(q0.y),acc0.z); acc0.w = fmaf(w0,bf_hi(q0.y),acc0.w); den0 += w0;
    acc1.x = fmaf(w1,bf_lo(q1.x),acc1.x); acc1.y = fmaf(w1,bf_hi(q1.x),acc1.y);
    acc1.z = fmaf(w1,bf_lo(q1.y),acc1.z); acc1.w = fmaf(w1,bf_hi(q1.y),acc1.w); den1 += w1;
    acc2.x = fmaf(w2,bf_lo(q2.x),acc2.x); acc2.y = fmaf(w2,bf_hi(q2.x),acc2.y);
    acc2.z = fmaf(w2,bf_lo(q2.y),acc2.z); acc2.w = fmaf(w2,bf_hi(q2.y),acc2.w); den2 += w2;
    acc3.x = fmaf(w3,bf_lo(q3.x),acc3.x); acc3.y = fmaf(w3,bf_hi(q3.x),acc3.y);
    acc3.z = fmaf(w3,bf_lo(q3.y),acc3.z); acc3.w = fmaf(w3,bf_hi(q3.y),acc3.w); den3 += w3;
  }
  for(; e < e1; e++){
    int s = ssrc[e];
    float w = ew[(size_t)e*4 + h];
    uint2 q = feat2[(size_t)s*64 + lane];
    acc0.x = fmaf(w,bf_lo(q.x),acc0.x); acc0.y = fmaf(w,bf_hi(q.x),acc0.y);
    acc0.z = fmaf(w,bf_lo(q.y),acc0.z); acc0.w = fmaf(w,bf_hi(q.y),acc0.w); den0 += w;
  }
  float denom = (den0+den1) + (den2+den3);
  float4 acc;
  acc.x = (acc0.x+acc1.x) + (acc2.x+acc3.x);
  acc.y = (acc0.y+acc1.y) + (acc2.y+acc3.y);
  acc.z = (acc0.z+acc1.z) + (acc2.z+acc3.z);
  acc.w = (acc0.w+acc1.w) + (acc2.w+acc3.w);
  float inv = 1.f / fmaxf(denom, 1e-9f);
  float4 b4 = *(const float4*)&bias[lane*4];
  float o0 = elu(acc.x*inv + b4.x);
  float o1 = elu(acc.y*inv + b4.y);
  float o2 = elu(acc.z*inv + b4.z);
  float o3 = elu(acc.w*inv + b4.w);
  ushortT h0=f2bf(o0), h1=f2bf(o1), h2=f2bf(o2), h3=f2bf(o3);
  ushort4 hv = make_ushort4(h0,h1,h2,h3);
  ushort4 lv = make_ushort4(f2bf(o0-bf2f(h0)), f2bf(o1-bf2f(h1)),
                            f2bf(o2-bf2f(h2)), f2bf(o3-bf2f(h3)));
  // A-plane store: lane owns k = lane*4..+3  ->  t = lane>>3, chunk offset (lane&7)*4
  int t8 = lane >> 3;
  int co = (lane & 7) * 4;
  size_t ad = ((size_t)t8*Mpad + n)*32 + co;
  *(ushort4*)&Hh[ad] = hv;
  *(ushort4*)&Hl[ad] = lv;
}

// ---------------- layer 2: aggregate (H*C=160 bf16) + head-mean logits ----------------
__global__ __launch_bounds__(256) void agg2_kernel(const uint2* __restrict__ feat2,
                            const float* __restrict__ ew,
                            const int* __restrict__ offsets, const int* __restrict__ ssrc,
                            const float* __restrict__ bias, float* __restrict__ logits, int N){
  __shared__ float s_out[4][160];
  int wv = threadIdx.x >> 6;
  int lane = threadIdx.x & 63;
  int n = blockIdx.x*4 + wv;
  bool valid = (n < N);
  if(valid && lane < 40){
    int h = lane / 10;
    int e0 = offsets[n], e1 = offsets[n+1];
    float4 acc0 = make_float4(0.f,0.f,0.f,0.f), acc1 = acc0, acc2 = acc0, acc3 = acc0;
    float den0 = 0.f, den1 = 0.f, den2 = 0.f, den3 = 0.f;
    int e = e0;
    for(; e+3 < e1; e += 4){
      int s0 = ssrc[e], s1 = ssrc[e+1], s2 = ssrc[e+2], s3 = ssrc[e+3];
      float w0 = ew[(size_t)e*4 + h];
      float w1 = ew[(size_t)(e+1)*4 + h];
      float w2 = ew[(size_t)(e+2)*4 + h];
      float w3 = ew[(size_t)(e+3)*4 + h];
      uint2 q0 = feat2[(size_t)s0*40 + lane];
      uint2 q1 = feat2[(size_t)s1*40 + lane];
      uint2 q2 = feat2[(size_t)s2*40 + lane];
      uint2 q3 = feat2[(size_t)s3*40 + lane];
      acc0.x = fmaf(w0,bf_lo(q0.x),acc0.x); acc0.y = fmaf(w0,bf_hi(q0.x),acc0.y);
      acc0.z = fmaf(w0,bf_lo(q0.y),acc0.z); acc0.w = fmaf(w0,bf_hi(q0.y),acc0.w); den0 += w0;
      acc1.x = fmaf(w1,bf_lo(q1.x),acc1.x); acc1.y = fmaf(w1,bf_hi(q1.x),acc1.y);
      acc1.z = fmaf(w1,bf_lo(q1.y),acc1.z); acc1.w = fmaf(w1,bf_hi(q1.y),acc1.w); den1 += w1;
      acc2.x = fmaf(w2,bf_lo(q2.x),acc2.x); acc2.y = fmaf(w2,bf_hi(q2.x),acc2.y);
      acc2.z = fmaf(w2,bf_lo(q2.y),acc2.z); acc2.w = fmaf(w2,bf_hi(q2.y),acc2.w); den2 += w2;
      acc3.x = fmaf(w3,bf_lo(q3.x),acc3.x); acc3.y = fmaf(w3,bf_hi(q3.x),acc3.y);
      acc3.z = fmaf(w3,bf_lo(q3.y),acc3.z); acc3.w = fmaf(w3,bf_hi(q3.y),acc3.w); den3 += w3;
    }
    for(; e < e1; e++){
      int s = ssrc[e];
      float w = ew[(size_t)e*4 + h];
      uint2 q = feat2[(size_t)s*40 + lane];
      acc0.x = fmaf(w,bf_lo(q.x),acc0.x); acc0.y = fmaf(w,bf_hi(q.x),acc0.y);
      acc0.z = fmaf(w,bf_lo(q.y),acc0.z); acc0.w = fmaf(w,bf_hi(q.y),acc0.w); den0 += w;
    }
    float denom = (den0+den1) + (den2+den3);
    float4 acc;
    acc.x = (acc0.x+acc1.x) + (acc2.x+acc3.x);
    acc.y = (acc0.y+acc1.y) + (acc2.y+acc3.y);
    acc.z = (acc0.z+acc1.z) + (acc2.z+acc3.z);
    acc.w = (acc0.w+acc1.w) + (acc2.w+acc3.w);
    float inv = 1.f / fmaxf(denom, 1e-9f);
    float4 b4 = *(const float4*)&bias[lane*4];
    s_out[wv][lane*4+0] = acc.x*inv + b4.x;
    s_out[wv][lane*4+1] = acc.y*inv + b4.y;
    s_out[wv][lane*4+2] = acc.z*inv + b4.z;
    s_out[wv][lane*4+3] = acc.w*inv + b4.w;
  }
  __syncthreads();
  if(valid && lane < 40){
    logits[(size_t)n*40 + lane] =
        0.25f * (s_out[wv][lane] + s_out[wv][40+lane] + s_out[wv][80+lane] + s_out[wv][120+lane]);
  }
}

extern "C" void kernel_launch(void* const* d_in, const int* in_sizes, int n_in,
                              void* d_out, int out_size, void* d_ws, size_t ws_size,
                              hipStream_t stream){
  const float* x   = (const float*)d_in[0];
  const int*   eix = (const int*)  d_in[1];
  const float* W0  = (const float*)d_in[2];
  const float* al0 = (const float*)d_in[3];
  const float* ar0 = (const float*)d_in[4];
  const float* b0  = (const float*)d_in[5];
  const float* W1  = (const float*)d_in[6];
  const float* al1 = (const float*)d_in[7];
  const float* ar1 = (const float*)d_in[8];
  const float* b1  = (const float*)d_in[9];
  const float* W2  = (const float*)d_in[10];
  const float* al2 = (const float*)d_in[11];
  const float* ar2 = (const float*)d_in[12];
  const float* b2  = (const float*)d_in[13];
  float* logits = (float*)d_out;

  const int N = in_sizes[0] / 256;   // 50000
  const int E = in_sizes[1] / 2;     // 800000
  const int* src = eix;
  const int* dst = eix + E;
  const int nb = (N + 1023) / 1024;

  char* ws = (char*)d_ws;
  auto alloc = [&](size_t bytes)->char*{
    char* p = ws; ws += (bytes + 255) & ~(size_t)255; return p;
  };
  const int nblocksM = (N + 127)/128;          // gemm M-blocks
  const int Mpad = nblocksM * 128;
  const size_t apackElems = (size_t)Mpad * 256;
  int*   counts    = (int*)  alloc((size_t)N*4);
  int*   offsets   = (int*)  alloc((size_t)(N+1)*4);
  int*   cursor    = (int*)  alloc((size_t)N*4);
  int*   blocksums = (int*)  alloc((size_t)nb*4);
  int*   ssrc      = (int*)  alloc((size_t)E*4);
  int*   sdst      = (int*)  alloc((size_t)E*4);
  float* ew        = (float*)alloc((size_t)E*4*4);
  __hip_bfloat16* bufF = (__hip_bfloat16*)alloc((size_t)N*256*2);   // gemm output (bf16, row-major)
  ushortT* Hh      = (ushortT*)alloc(apackElems*2);                  // A hi plane [t][Mpad][32]
  ushortT* Hl      = (ushortT*)alloc(apackElems*2);                  // A lo plane
  float* el_buf    = (float*)alloc((size_t)N*4*4);
  float* er_buf    = (float*)alloc((size_t)N*4*4);
  ushortT* Wph0 = (ushortT*)alloc(16*8*64*8*2);
  ushortT* Wpl0 = (ushortT*)alloc(16*8*64*8*2);
  ushortT* Wph1 = (ushortT*)alloc(16*8*64*8*2);
  ushortT* Wpl1 = (ushortT*)alloc(16*8*64*8*2);
  ushortT* Wph2 = (ushortT*)alloc(16*8*64*8*2);
  ushortT* Wpl2 = (ushortT*)alloc(16*8*64*8*2);

  // sort edges by dst (graph fixed across layers — one sort per call)
  hipMemsetAsync(counts, 0, (size_t)N*4, stream);
  hist_kernel   <<<(E+255)/256, 256, 0, stream>>>(dst, E, counts);
  scan1_kernel  <<<nb, 1024, 0, stream>>>(counts, N, offsets, blocksums);
  scan2_kernel  <<<1, 64, 0, stream>>>(blocksums, nb);
  scan3_kernel  <<<nb, 1024, 0, stream>>>(offsets, blocksums, N, E, cursor);
  scatter_kernel<<<(E+255)/256, 256, 0, stream>>>(src, dst, E, cursor, ssrc, sdst);

  // weight + x packing (fragment order, hi/lo split)
  wsplit_pack<<<32, 256, 0, stream>>>(W0, 256, Wph0, Wpl0);
  wsplit_pack<<<32, 256, 0, stream>>>(W1, 256, Wph1, Wpl1);
  wsplit_pack<<<32, 256, 0, stream>>>(W2, 160, Wph2, Wpl2);
  int xtotal = 8 * Mpad;
  xsplit_pack<<<(xtotal+255)/256, 256, 0, stream>>>(x, N, Mpad, Hh, Hl);

  dim3 gg01(4, nblocksM);          // layers 0/1: 4 col-tiles of 64 (= heads)
  dim3 gg2 (3, nblocksM);          // layer 2: 160 cols -> 3 col-tiles (guarded)
  int aggGrid = (N+3)/4;
  int ewGrid  = (E+255)/256;
  // layer 0 (el/er fused in gemm epilogue)
  gemm_packed<<<gg01, 256, 0, stream>>>(Hh, Hl, Wph0, Wpl0, (ushortT*)bufF, N, Mpad, 256, al0, ar0, el_buf, er_buf);
  edge_w_kernel<<<ewGrid, 256, 0, stream>>>(ssrc, sdst, E, (const float4*)el_buf, (const float4*)er_buf, (float4*)ew);
  agg_kernel<<<aggGrid, 256, 0, stream>>>((const uint2*)bufF, ew, offsets, ssrc, b0, Hh, Hl, N, Mpad);
  // layer 1
  gemm_packed<<<gg01, 256, 0, stream>>>(Hh, Hl, Wph1, Wpl1, (ushortT*)bufF, N, Mpad, 256, al1, ar1, el_buf, er_buf);
  edge_w_kernel<<<ewGrid, 256, 0, stream>>>(ssrc, sdst, E, (const float4*)el_buf, (const float4*)er_buf, (float4*)ew);
  agg_kernel<<<aggGrid, 256, 0, stream>>>((const uint2*)bufF, ew, offsets, ssrc, b1, Hh, Hl, N, Mpad);
  // layer 2 (heads are 40-wide — separate attn_proj on bf16 feat)
  gemm_packed<<<gg2, 256, 0, stream>>>(Hh, Hl, Wph2, Wpl2, (ushortT*)bufF, N, Mpad, 160, nullptr, nullptr, nullptr, nullptr);
  attn_proj_bf<<<N, 256, 0, stream>>>(bufF, al2, ar2, el_buf, er_buf, 40);
  edge_w_kernel<<<ewGrid, 256, 0, stream>>>(ssrc, sdst, E, (const float4*)el_buf, (const float4*)er_buf, (float4*)ew);
  agg2_kernel<<<aggGrid, 256, 0, stream>>>((const uint2*)bufF, ew, offsets, ssrc, b2, logits, N);
}

// Round 10
// 565.970 us; speedup vs baseline: 1.1661x; 1.0069x over previous
//
#include <hip/hip_runtime.h>
#include <hip/hip_bf16.h>
#include <math.h>

#define NEG_SLOPE 0.2f

typedef unsigned short ushortT;
typedef __attribute__((ext_vector_type(8))) short short8;   // 8 bf16 = 4 VGPRs (MFMA A/B frag)
typedef __attribute__((ext_vector_type(4))) float f32x4;    // MFMA C/D frag

static __device__ __forceinline__ float leaky(float x){ return x > 0.f ? x : NEG_SLOPE * x; }
static __device__ __forceinline__ float elu(float x){ return x > 0.f ? x : (__expf(x) - 1.f); }

// bf16 helpers: RNE pack, exact unpack
static __device__ __forceinline__ ushortT f2bf(float f){
  unsigned u = __float_as_uint(f);
  u += 0x7fff + ((u >> 16) & 1);
  return (ushortT)(u >> 16);
}
static __device__ __forceinline__ float bf2f(ushortT h){ return __uint_as_float((unsigned)h << 16); }
static __device__ __forceinline__ float bf_lo(unsigned u){ return __uint_as_float(u << 16); }
static __device__ __forceinline__ float bf_hi(unsigned u){ return __uint_as_float(u & 0xffff0000u); }

// A-plane layout: elem (row,k) -> [ (k/32)*Mpad + row ]*32 + k%32
//   (GEMM frag-loadable AND 64B-line-contiguous for agg stores — zero RMW)
// B-plane layout: [(ntile*8 + t)*64 + lane]*8 (contiguous 1KB per wave frag)

// ---------------- edge sort by dst (counting sort) ----------------
__global__ void hist_kernel(const int* __restrict__ dst, int E, int* __restrict__ counts){
  int i = blockIdx.x*blockDim.x + threadIdx.x;
  if(i < E) atomicAdd(&counts[dst[i]], 1);
}

__global__ void scan1_kernel(const int* __restrict__ counts, int N,
                             int* __restrict__ offsets, int* __restrict__ blocksums){
  __shared__ int sdata[1024];
  int i = blockIdx.x*1024 + threadIdx.x;
  int v = (i<N) ? counts[i] : 0;
  sdata[threadIdx.x] = v;
  __syncthreads();
  for(int off=1; off<1024; off<<=1){
    int t = (threadIdx.x >= off) ? sdata[threadIdx.x-off] : 0;
    __syncthreads();
    sdata[threadIdx.x] += t;
    __syncthreads();
  }
  if(i<N) offsets[i] = sdata[threadIdx.x] - v;
  if(threadIdx.x==1023) blocksums[blockIdx.x] = sdata[1023];
}

__global__ void scan2_kernel(int* __restrict__ blocksums, int nb){
  __shared__ int sdata[64];
  int v = ((int)threadIdx.x < nb) ? blocksums[threadIdx.x] : 0;
  sdata[threadIdx.x] = v;
  __syncthreads();
  for(int off=1; off<64; off<<=1){
    int t = (threadIdx.x >= off) ? sdata[threadIdx.x-off] : 0;
    __syncthreads();
    sdata[threadIdx.x] += t;
    __syncthreads();
  }
  if((int)threadIdx.x < nb) blocksums[threadIdx.x] = sdata[threadIdx.x] - v;
}

__global__ void scan3_kernel(int* __restrict__ offsets, const int* __restrict__ blocksums,
                             int N, int E, int* __restrict__ cursor){
  int i = blockIdx.x*1024 + threadIdx.x;
  if(i < N){
    int o = offsets[i] + blocksums[blockIdx.x];
    offsets[i] = o;
    cursor[i] = o;
  }
  if(i == 0) offsets[N] = E;
}

__global__ void scatter_kernel(const int* __restrict__ src, const int* __restrict__ dst, int E,
                               int* __restrict__ cursor, int* __restrict__ ssrc,
                               int* __restrict__ sdst){
  int i = blockIdx.x*blockDim.x + threadIdx.x;
  if(i < E){
    int d = dst[i];
    int p = atomicAdd(&cursor[d], 1);
    ssrc[p] = src[i];
    sdst[p] = d;
  }
}

// ---------------- W split to packed fragment order: W[K=256, N] -> packed[16 ntiles] ----------------
__global__ __launch_bounds__(256) void wsplit_pack(const float* __restrict__ W, int N,
                              ushortT* __restrict__ Wh, ushortT* __restrict__ Wl){
  int idx = blockIdx.x*256 + threadIdx.x;     // < 16*8*64 = 8192
  int lane = idx & 63;
  int t  = (idx >> 6) & 7;
  int nt = idx >> 9;
  int l15 = lane & 15, quad = lane >> 4;
  int n = nt*16 + l15;
  ushortT h[8], l[8];
  #pragma unroll
  for(int j=0;j<8;j++){
    int k = t*32 + quad*8 + j;
    float v = (n < N) ? W[(size_t)k*N + n] : 0.f;
    h[j] = f2bf(v);
    l[j] = f2bf(v - bf2f(h[j]));
  }
  *(short8*)&Wh[(size_t)idx*8] = *(short8*)h;
  *(short8*)&Wl[(size_t)idx*8] = *(short8*)l;
}

// ---------------- x split fp32 [M][256] -> A-plane layout [t][Mpad][32] ----------------
__global__ __launch_bounds__(256) void xsplit_pack(const float* __restrict__ x, int M, int Mpad,
                              ushortT* __restrict__ Xh, ushortT* __restrict__ Xl){
  int idx = blockIdx.x*256 + threadIdx.x;     // over 8*Mpad, idx = t*Mpad + m
  if(idx >= 8*Mpad) return;
  int t = idx / Mpad, m = idx - t*Mpad;
  size_t base = (size_t)idx * 32;
  if(m < M){
    const float* xr = &x[(size_t)m*256 + t*32];
    #pragma unroll
    for(int c=0;c<4;c++){
      float4 v0 = *(const float4*)&xr[c*8];
      float4 v1 = *(const float4*)&xr[c*8+4];
      float vv[8] = {v0.x,v0.y,v0.z,v0.w,v1.x,v1.y,v1.z,v1.w};
      ushortT h[8], l[8];
      #pragma unroll
      for(int j=0;j<8;j++){
        h[j] = f2bf(vv[j]);
        l[j] = f2bf(vv[j] - bf2f(h[j]));
      }
      *(short8*)&Xh[base + c*8] = *(short8*)h;
      *(short8*)&Xl[base + c*8] = *(short8*)l;
    }
  } else {
    short8 z = {0,0,0,0,0,0,0,0};
    #pragma unroll
    for(int c=0;c<4;c++){ *(short8*)&Xh[base + c*8] = z; *(short8*)&Xl[base + c*8] = z; }
  }
}

// ---------------- bf16x3 MFMA GEMM, A read ONCE: block = 32 rows x full 256 cols ----------------
// 4 waves side-by-side in N (wave wv owns cols wv*64..+63); all waves share the same
// 32-row A-tile (32KB -> L1 reuse). B packed (256KB) is L2-resident broadcast.
// Layers 0/1 (al!=nullptr): wave's 64-col tile == head wv; fused el/er epilogue.
__global__ __launch_bounds__(256) void gemm_packed(
    const ushortT* __restrict__ Ah, const ushortT* __restrict__ Al,
    const ushortT* __restrict__ Bh, const ushortT* __restrict__ Bl,
    ushortT* __restrict__ Cm, int M, int Mpad, int N,
    const float* __restrict__ al, const float* __restrict__ ar,
    float* __restrict__ el, float* __restrict__ er){
  const int lane = threadIdx.x & 63;
  const int wv   = threadIdx.x >> 6;
  const int l15  = lane & 15, quad = lane >> 4;
  const int m0   = blockIdx.x*32;
  const int n0   = wv*64;
  const int nt0  = n0 >> 4;     // 4 ntiles per wave

  f32x4 acc[2][4];
  #pragma unroll
  for(int i=0;i<2;i++)
    #pragma unroll
    for(int j=0;j<4;j++){ acc[i][j][0]=0.f; acc[i][j][1]=0.f; acc[i][j][2]=0.f; acc[i][j][3]=0.f; }

  #pragma unroll
  for(int t=0; t<8; t++){
    short8 a_h[2], a_l[2], b_h[4], b_l[4];
    #pragma unroll
    for(int i=0;i<2;i++){
      size_t ad = ((size_t)t*Mpad + (m0 + i*16 + l15))*32 + quad*8;
      a_h[i] = *(const short8*)&Ah[ad];
      a_l[i] = *(const short8*)&Al[ad];
    }
    #pragma unroll
    for(int j=0;j<4;j++){
      size_t bd = (((size_t)(nt0+j)*8 + t)*64 + lane)*8;
      b_h[j] = *(const short8*)&Bh[bd];
      b_l[j] = *(const short8*)&Bl[bd];
    }
    #pragma unroll
    for(int i=0;i<2;i++)
      #pragma unroll
      for(int j=0;j<4;j++){
        acc[i][j] = __builtin_amdgcn_mfma_f32_16x16x32_bf16(a_h[i], b_h[j], acc[i][j], 0,0,0);
        acc[i][j] = __builtin_amdgcn_mfma_f32_16x16x32_bf16(a_h[i], b_l[j], acc[i][j], 0,0,0);
        acc[i][j] = __builtin_amdgcn_mfma_f32_16x16x32_bf16(a_l[i], b_h[j], acc[i][j], 0,0,0);
      }
  }

  // fused el/er (layers 0/1): this wave's col-tile is exactly head wv
  if(al){
    const int h = wv;
    float alv[4], arv[4];
    #pragma unroll
    for(int j=0;j<4;j++){
      alv[j] = al[h*64 + j*16 + l15];
      arv[j] = ar[h*64 + j*16 + l15];
    }
    #pragma unroll
    for(int i=0;i<2;i++){
      #pragma unroll
      for(int r=0;r<4;r++){
        float pl = acc[i][0][r]*alv[0] + acc[i][1][r]*alv[1]
                 + acc[i][2][r]*alv[2] + acc[i][3][r]*alv[3];
        float pr = acc[i][0][r]*arv[0] + acc[i][1][r]*arv[1]
                 + acc[i][2][r]*arv[2] + acc[i][3][r]*arv[3];
        #pragma unroll
        for(int off=1; off<16; off<<=1){ pl += __shfl_xor(pl,off); pr += __shfl_xor(pr,off); }
        int gm = m0 + i*16 + quad*4 + r;
        if(l15==0 && gm < M){ el[gm*4+h] = pl; er[gm*4+h] = pr; }
      }
    }
  }

  // C store, row-major bf16.  C/D layout: col=lane&15, row=quad*4+r
  #pragma unroll
  for(int i=0;i<2;i++){
    #pragma unroll
    for(int r=0;r<4;r++){
      int gm = m0 + i*16 + quad*4 + r;
      if(gm >= M) continue;
      #pragma unroll
      for(int j=0;j<4;j++){
        int gn = n0 + j*16 + l15;
        if(gn < N) Cm[(size_t)gm*N + gn] = f2bf(acc[i][j][r]);
      }
    }
  }
}

// ---------------- el/er projection from bf16 feat (layer 2 only) ----------------
__global__ void attn_proj_bf(const __hip_bfloat16* __restrict__ feat, const float* __restrict__ a_l,
                             const float* __restrict__ a_r, float* __restrict__ el,
                             float* __restrict__ er, int D){
  int n = blockIdx.x;
  int h = threadIdx.x >> 6;
  int lane = threadIdx.x & 63;
  float vl = 0.f, vr = 0.f;
  for(int d=lane; d<D; d+=64){
    float f = (float)feat[(size_t)n*4*D + h*D + d];
    vl = fmaf(f, a_l[h*D+d], vl);
    vr = fmaf(f, a_r[h*D+d], vr);
  }
  #pragma unroll
  for(int off=32; off; off>>=1){ vl += __shfl_down(vl,off); vr += __shfl_down(vr,off); }
  if(lane==0){ el[n*4+h] = vl; er[n*4+h] = vr; }
}

// ---------------- per-edge softmax numerators (all 4 heads) ----------------
__global__ __launch_bounds__(256) void edge_w_kernel(const int* __restrict__ ssrc,
                              const int* __restrict__ sdst, int E,
                              const float4* __restrict__ el4, const float4* __restrict__ er4,
                              float4* __restrict__ ew){
  int e = blockIdx.x*blockDim.x + threadIdx.x;
  if(e >= E) return;
  int s = ssrc[e], d = sdst[e];
  float4 l = el4[s], r = er4[d];
  float4 w;
  w.x = __expf(leaky(l.x + r.x));
  w.y = __expf(leaky(l.y + r.y));
  w.z = __expf(leaky(l.z + r.z));
  w.w = __expf(leaky(l.w + r.w));
  ew[e] = w;
}

// ---------------- softmax + aggregate, layers 0/1 (H*D=256 bf16), ELU ----------------
// one WAVE per dst node; epilogue writes next-layer A planes in [t][Mpad][32] layout:
// node n writes 8 full 64B lines per plane (zero RMW).
__global__ __launch_bounds__(256) void agg_kernel(const uint2* __restrict__ feat2,
                           const float* __restrict__ ew,
                           const int* __restrict__ offsets, const int* __restrict__ ssrc,
                           const float* __restrict__ bias,
                           ushortT* __restrict__ Hh, ushortT* __restrict__ Hl, int N, int Mpad){
  int wv = threadIdx.x >> 6;
  int lane = threadIdx.x & 63;
  int n = blockIdx.x*4 + wv;
  if(n >= N) return;
  int h = lane >> 4;
  int e0 = offsets[n], e1 = offsets[n+1];
  float4 acc0 = make_float4(0.f,0.f,0.f,0.f), acc1 = acc0, acc2 = acc0, acc3 = acc0;
  float den0 = 0.f, den1 = 0.f, den2 = 0.f, den3 = 0.f;
  int e = e0;
  for(; e+3 < e1; e += 4){
    int s0 = ssrc[e], s1 = ssrc[e+1], s2 = ssrc[e+2], s3 = ssrc[e+3];
    float w0 = ew[(size_t)e*4 + h];
    float w1 = ew[(size_t)(e+1)*4 + h];
    float w2 = ew[(size_t)(e+2)*4 + h];
    float w3 = ew[(size_t)(e+3)*4 + h];
    uint2 q0 = feat2[(size_t)s0*64 + lane];
    uint2 q1 = feat2[(size_t)s1*64 + lane];
    uint2 q2 = feat2[(size_t)s2*64 + lane];
    uint2 q3 = feat2[(size_t)s3*64 + lane];
    acc0.x = fmaf(w0,bf_lo(q0.x),acc0.x); acc0.y = fmaf(w0,bf_hi(q0.x),acc0.y);
    acc0.z = fmaf(w0,bf_lo(q0.y),acc0.z); acc0.w = fmaf(w0,bf_hi(q0.y),acc0.w); den0 += w0;
    acc1.x = fmaf(w1,bf_lo(q1.x),acc1.x); acc1.y = fmaf(w1,bf_hi(q1.x),acc1.y);
    acc1.z = fmaf(w1,bf_lo(q1.y),acc1.z); acc1.w = fmaf(w1,bf_hi(q1.y),acc1.w); den1 += w1;
    acc2.x = fmaf(w2,bf_lo(q2.x),acc2.x); acc2.y = fmaf(w2,bf_hi(q2.x),acc2.y);
    acc2.z = fmaf(w2,bf_lo(q2.y),acc2.z); acc2.w = fmaf(w2,bf_hi(q2.y),acc2.w); den2 += w2;
    acc3.x = fmaf(w3,bf_lo(q3.x),acc3.x); acc3.y = fmaf(w3,bf_hi(q3.x),acc3.y);
    acc3.z = fmaf(w3,bf_lo(q3.y),acc3.z); acc3.w = fmaf(w3,bf_hi(q3.y),acc3.w); den3 += w3;
  }
  for(; e < e1; e++){
    int s = ssrc[e];
    float w = ew[(size_t)e*4 + h];
    uint2 q = feat2[(size_t)s*64 + lane];
    acc0.x = fmaf(w,bf_lo(q.x),acc0.x); acc0.y = fmaf(w,bf_hi(q.x),acc0.y);
    acc0.z = fmaf(w,bf_lo(q.y),acc0.z); acc0.w = fmaf(w,bf_hi(q.y),acc0.w); den0 += w;
  }
  float denom = (den0+den1) + (den2+den3);
  float4 acc;
  acc.x = (acc0.x+acc1.x) + (acc2.x+acc3.x);
  acc.y = (acc0.y+acc1.y) + (acc2.y+acc3.y);
  acc.z = (acc0.z+acc1.z) + (acc2.z+acc3.z);
  acc.w = (acc0.w+acc1.w) + (acc2.w+acc3.w);
  float inv = 1.f / fmaxf(denom, 1e-9f);
  float4 b4 = *(const float4*)&bias[lane*4];
  float o0 = elu(acc.x*inv + b4.x);
  float o1 = elu(acc.y*inv + b4.y);
  float o2 = elu(acc.z*inv + b4.z);
  float o3 = elu(acc.w*inv + b4.w);
  ushortT h0=f2bf(o0), h1=f2bf(o1), h2=f2bf(o2), h3=f2bf(o3);
  ushort4 hv = make_ushort4(h0,h1,h2,h3);
  ushort4 lv = make_ushort4(f2bf(o0-bf2f(h0)), f2bf(o1-bf2f(h1)),
                            f2bf(o2-bf2f(h2)), f2bf(o3-bf2f(h3)));
  // A-plane store: lane owns k = lane*4..+3  ->  t = lane>>3, chunk offset (lane&7)*4
  int t8 = lane >> 3;
  int co = (lane & 7) * 4;
  size_t ad = ((size_t)t8*Mpad + n)*32 + co;
  *(ushort4*)&Hh[ad] = hv;
  *(ushort4*)&Hl[ad] = lv;
}

// ---------------- layer 2: aggregate (H*C=160 bf16) + head-mean logits ----------------
__global__ __launch_bounds__(256) void agg2_kernel(const uint2* __restrict__ feat2,
                            const float* __restrict__ ew,
                            const int* __restrict__ offsets, const int* __restrict__ ssrc,
                            const float* __restrict__ bias, float* __restrict__ logits, int N){
  __shared__ float s_out[4][160];
  int wv = threadIdx.x >> 6;
  int lane = threadIdx.x & 63;
  int n = blockIdx.x*4 + wv;
  bool valid = (n < N);
  if(valid && lane < 40){
    int h = lane / 10;
    int e0 = offsets[n], e1 = offsets[n+1];
    float4 acc0 = make_float4(0.f,0.f,0.f,0.f), acc1 = acc0, acc2 = acc0, acc3 = acc0;
    float den0 = 0.f, den1 = 0.f, den2 = 0.f, den3 = 0.f;
    int e = e0;
    for(; e+3 < e1; e += 4){
      int s0 = ssrc[e], s1 = ssrc[e+1], s2 = ssrc[e+2], s3 = ssrc[e+3];
      float w0 = ew[(size_t)e*4 + h];
      float w1 = ew[(size_t)(e+1)*4 + h];
      float w2 = ew[(size_t)(e+2)*4 + h];
      float w3 = ew[(size_t)(e+3)*4 + h];
      uint2 q0 = feat2[(size_t)s0*40 + lane];
      uint2 q1 = feat2[(size_t)s1*40 + lane];
      uint2 q2 = feat2[(size_t)s2*40 + lane];
      uint2 q3 = feat2[(size_t)s3*40 + lane];
      acc0.x = fmaf(w0,bf_lo(q0.x),acc0.x); acc0.y = fmaf(w0,bf_hi(q0.x),acc0.y);
      acc0.z = fmaf(w0,bf_lo(q0.y),acc0.z); acc0.w = fmaf(w0,bf_hi(q0.y),acc0.w); den0 += w0;
      acc1.x = fmaf(w1,bf_lo(q1.x),acc1.x); acc1.y = fmaf(w1,bf_hi(q1.x),acc1.y);
      acc1.z = fmaf(w1,bf_lo(q1.y),acc1.z); acc1.w = fmaf(w1,bf_hi(q1.y),acc1.w); den1 += w1;
      acc2.x = fmaf(w2,bf_lo(q2.x),acc2.x); acc2.y = fmaf(w2,bf_hi(q2.x),acc2.y);
      acc2.z = fmaf(w2,bf_lo(q2.y),acc2.z); acc2.w = fmaf(w2,bf_hi(q2.y),acc2.w); den2 += w2;
      acc3.x = fmaf(w3,bf_lo(q3.x),acc3.x); acc3.y = fmaf(w3,bf_hi(q3.x),acc3.y);
      acc3.z = fmaf(w3,bf_lo(q3.y),acc3.z); acc3.w = fmaf(w3,bf_hi(q3.y),acc3.w); den3 += w3;
    }
    for(; e < e1; e++){
      int s = ssrc[e];
      float w = ew[(size_t)e*4 + h];
      uint2 q = feat2[(size_t)s*40 + lane];
      acc0.x = fmaf(w,bf_lo(q.x),acc0.x); acc0.y = fmaf(w,bf_hi(q.x),acc0.y);
      acc0.z = fmaf(w,bf_lo(q.y),acc0.z); acc0.w = fmaf(w,bf_hi(q.y),acc0.w); den0 += w;
    }
    float denom = (den0+den1) + (den2+den3);
    float4 acc;
    acc.x = (acc0.x+acc1.x) + (acc2.x+acc3.x);
    acc.y = (acc0.y+acc1.y) + (acc2.y+acc3.y);
    acc.z = (acc0.z+acc1.z) + (acc2.z+acc3.z);
    acc.w = (acc0.w+acc1.w) + (acc2.w+acc3.w);
    float inv = 1.f / fmaxf(denom, 1e-9f);
    float4 b4 = *(const float4*)&bias[lane*4];
    s_out[wv][lane*4+0] = acc.x*inv + b4.x;
    s_out[wv][lane*4+1] = acc.y*inv + b4.y;
    s_out[wv][lane*4+2] = acc.z*inv + b4.z;
    s_out[wv][lane*4+3] = acc.w*inv + b4.w;
  }
  __syncthreads();
  if(valid && lane < 40){
    logits[(size_t)n*40 + lane] =
        0.25f * (s_out[wv][lane] + s_out[wv][40+lane] + s_out[wv][80+lane] + s_out[wv][120+lane]);
  }
}

extern "C" void kernel_launch(void* const* d_in, const int* in_sizes, int n_in,
                              void* d_out, int out_size, void* d_ws, size_t ws_size,
                              hipStream_t stream){
  const float* x   = (const float*)d_in[0];
  const int*   eix = (const int*)  d_in[1];
  const float* W0  = (const float*)d_in[2];
  const float* al0 = (const float*)d_in[3];
  const float* ar0 = (const float*)d_in[4];
  const float* b0  = (const float*)d_in[5];
  const float* W1  = (const float*)d_in[6];
  const float* al1 = (const float*)d_in[7];
  const float* ar1 = (const float*)d_in[8];
  const float* b1  = (const float*)d_in[9];
  const float* W2  = (const float*)d_in[10];
  const float* al2 = (const float*)d_in[11];
  const float* ar2 = (const float*)d_in[12];
  const float* b2  = (const float*)d_in[13];
  float* logits = (float*)d_out;

  const int N = in_sizes[0] / 256;   // 50000
  const int E = in_sizes[1] / 2;     // 800000
  const int* src = eix;
  const int* dst = eix + E;
  const int nb = (N + 1023) / 1024;

  char* ws = (char*)d_ws;
  auto alloc = [&](size_t bytes)->char*{
    char* p = ws; ws += (bytes + 255) & ~(size_t)255; return p;
  };
  const int nblocksM = (N + 127)/128;
  const int Mpad = nblocksM * 128;
  const size_t apackElems = (size_t)Mpad * 256;
  int*   counts    = (int*)  alloc((size_t)N*4);
  int*   offsets   = (int*)  alloc((size_t)(N+1)*4);
  int*   cursor    = (int*)  alloc((size_t)N*4);
  int*   blocksums = (int*)  alloc((size_t)nb*4);
  int*   ssrc      = (int*)  alloc((size_t)E*4);
  int*   sdst      = (int*)  alloc((size_t)E*4);
  float* ew        = (float*)alloc((size_t)E*4*4);
  __hip_bfloat16* bufF = (__hip_bfloat16*)alloc((size_t)N*256*2);   // gemm output (bf16, row-major)
  ushortT* Hh      = (ushortT*)alloc(apackElems*2);                  // A hi plane [t][Mpad][32]
  ushortT* Hl      = (ushortT*)alloc(apackElems*2);                  // A lo plane
  float* el_buf    = (float*)alloc((size_t)N*4*4);
  float* er_buf    = (float*)alloc((size_t)N*4*4);
  ushortT* Wph0 = (ushortT*)alloc(16*8*64*8*2);
  ushortT* Wpl0 = (ushortT*)alloc(16*8*64*8*2);
  ushortT* Wph1 = (ushortT*)alloc(16*8*64*8*2);
  ushortT* Wpl1 = (ushortT*)alloc(16*8*64*8*2);
  ushortT* Wph2 = (ushortT*)alloc(16*8*64*8*2);
  ushortT* Wpl2 = (ushortT*)alloc(16*8*64*8*2);

  // sort edges by dst (graph fixed across layers — one sort per call)
  hipMemsetAsync(counts, 0, (size_t)N*4, stream);
  hist_kernel   <<<(E+255)/256, 256, 0, stream>>>(dst, E, counts);
  scan1_kernel  <<<nb, 1024, 0, stream>>>(counts, N, offsets, blocksums);
  scan2_kernel  <<<1, 64, 0, stream>>>(blocksums, nb);
  scan3_kernel  <<<nb, 1024, 0, stream>>>(offsets, blocksums, N, E, cursor);
  scatter_kernel<<<(E+255)/256, 256, 0, stream>>>(src, dst, E, cursor, ssrc, sdst);

  // weight + x packing (fragment order, hi/lo split)
  wsplit_pack<<<32, 256, 0, stream>>>(W0, 256, Wph0, Wpl0);
  wsplit_pack<<<32, 256, 0, stream>>>(W1, 256, Wph1, Wpl1);
  wsplit_pack<<<32, 256, 0, stream>>>(W2, 160, Wph2, Wpl2);
  int xtotal = 8 * Mpad;
  xsplit_pack<<<(xtotal+255)/256, 256, 0, stream>>>(x, N, Mpad, Hh, Hl);

  int ggBlocks = Mpad / 32;        // block = 32 rows x full-N; A read exactly once
  int aggGrid = (N+3)/4;
  int ewGrid  = (E+255)/256;
  // layer 0 (el/er fused in gemm epilogue)
  gemm_packed<<<ggBlocks, 256, 0, stream>>>(Hh, Hl, Wph0, Wpl0, (ushortT*)bufF, N, Mpad, 256, al0, ar0, el_buf, er_buf);
  edge_w_kernel<<<ewGrid, 256, 0, stream>>>(ssrc, sdst, E, (const float4*)el_buf, (const float4*)er_buf, (float4*)ew);
  agg_kernel<<<aggGrid, 256, 0, stream>>>((const uint2*)bufF, ew, offsets, ssrc, b0, Hh, Hl, N, Mpad);
  // layer 1
  gemm_packed<<<ggBlocks, 256, 0, stream>>>(Hh, Hl, Wph1, Wpl1, (ushortT*)bufF, N, Mpad, 256, al1, ar1, el_buf, er_buf);
  edge_w_kernel<<<ewGrid, 256, 0, stream>>>(ssrc, sdst, E, (const float4*)el_buf, (const float4*)er_buf, (float4*)ew);
  agg_kernel<<<aggGrid, 256, 0, stream>>>((const uint2*)bufF, ew, offsets, ssrc, b1, Hh, Hl, N, Mpad);
  // layer 2 (N=160: waves 2/3 partially idle on zero-padded B cols; stores guarded)
  gemm_packed<<<ggBlocks, 256, 0, stream>>>(Hh, Hl, Wph2, Wpl2, (ushortT*)bufF, N, Mpad, 160, nullptr, nullptr, nullptr, nullptr);
  attn_proj_bf<<<N, 256, 0, stream>>>(bufF, al2, ar2, el_buf, er_buf, 40);
  edge_w_kernel<<<ewGrid, 256, 0, stream>>>(ssrc, sdst, E, (const float4*)el_buf, (const float4*)er_buf, (float4*)ew);
  agg2_kernel<<<aggGrid, 256, 0, stream>>>((const uint2*)bufF, ew, offsets, ssrc, b2, logits, N);
}